// Round 1
// baseline (312.381 us; speedup 1.0000x reference)
//
#include <hip/hip_runtime.h>
#include <hip/hip_bf16.h>
#include <math.h>

#define T_TOK 8192
#define D_MODEL 2048
#define N_EXP 16
#define CAP 512
#define NSEG (T_TOK / 64)           // 128

// ws layout (bytes):
// aff:   0       .. 524288    float[T_TOK][16]
// pref:  524288  .. +65536    u64[T_TOK]
// probs: 589824  .. +524288   float[T_TOK][16]
// evt:   1114112 .. +128      int[32] (evp[16], evf[16])
// t2e:   1114240 .. +8192     u8[T_TOK]
// bcnt:  1122432 .. +2048     int[32][16]

__device__ __forceinline__ unsigned int f2ord(float f) {
    unsigned int b = __float_as_uint(f);
    return (b & 0x80000000u) ? ~b : (b | 0x80000000u);
}

// ---------------- Kernel 1: GEMM, 2 tokens/wave (no spill), W double-buffered in LDS ----------------
// 1024 blocks x 256 thr; wave owns 2 tokens; lane slices K (32 floats: j*256 + lane*4).
// Per j-chunk (256 floats of K): W chunk [16][256] staged in LDS (16 KiB), double-buffered.
// Numerics are bit-identical to the previous verified kernel: same per-lane K slice, same
// FMA ordering, same butterfly pairing order (m=1,2,4,8,16 then 32).
__global__ __launch_bounds__(256, 4) void gemm_aff_kernel(
    const float* __restrict__ feat, const float* __restrict__ W,
    float* __restrict__ aff)
{
    __shared__ float wlds[2][N_EXP][256];   // 32 KiB

    const int tid  = threadIdx.x;
    const int wave = tid >> 6, lane = tid & 63;
    const int tbase = blockIdx.x * 8 + wave * 2;

    const float* fbase = feat + (size_t)tbase * D_MODEL + lane * 4;
    // this thread stages experts wave*4 .. wave*4+3, floats [lane*4, lane*4+4) of each chunk
    const float* wsrc0 = W + (size_t)(wave * 4) * D_MODEL + lane * 4;

    float acc[32];   // acc[r*16+e], r in {0,1}
    #pragma unroll
    for (int i = 0; i < 32; ++i) acc[i] = 0.f;

    // ---- prologue: stage W chunk 0 into buf 0; load first feature chunk ----
    float4 wstage[4];
    #pragma unroll
    for (int i = 0; i < 4; ++i)
        wstage[i] = *(const float4*)(wsrc0 + (size_t)i * D_MODEL);

    float4 cur[2], nxt[2];
    #pragma unroll
    for (int r = 0; r < 2; ++r)
        cur[r] = *(const float4*)(fbase + (size_t)r * D_MODEL);

    #pragma unroll
    for (int i = 0; i < 4; ++i)
        *(float4*)(&wlds[0][wave * 4 + i][0] + lane * 4) = wstage[i];
    __syncthreads();

    #pragma unroll
    for (int j = 0; j < 8; ++j) {               // 8 k-chunks of 256 floats
        // issue next chunk's global loads early (hide HBM/L2 latency under compute)
        if (j < 7) {
            #pragma unroll
            for (int i = 0; i < 4; ++i)
                wstage[i] = *(const float4*)(wsrc0 + (size_t)i * D_MODEL + (j + 1) * 256);
            #pragma unroll
            for (int r = 0; r < 2; ++r)
                nxt[r] = *(const float4*)(fbase + (size_t)r * D_MODEL + (j + 1) * 256);
        }

        // compute on current buffer
        const float* wl = &wlds[j & 1][0][0] + lane * 4;
        #pragma unroll
        for (int g = 0; g < 4; ++g) {           // experts in groups of 4 (reg pressure)
            float4 wv[4];
            #pragma unroll
            for (int i = 0; i < 4; ++i)
                wv[i] = *(const float4*)(wl + (g * 4 + i) * 256);
            #pragma unroll
            for (int i = 0; i < 4; ++i)
                #pragma unroll
                for (int r = 0; r < 2; ++r) {
                    acc[r * 16 + g * 4 + i] += cur[r].x * wv[i].x;
                    acc[r * 16 + g * 4 + i] += cur[r].y * wv[i].y;
                    acc[r * 16 + g * 4 + i] += cur[r].z * wv[i].z;
                    acc[r * 16 + g * 4 + i] += cur[r].w * wv[i].w;
                }
        }

        // write next chunk into the other buffer (safe: all waves done reading it
        // since the barrier at the end of iteration j-1)
        if (j < 7) {
            #pragma unroll
            for (int i = 0; i < 4; ++i)
                *(float4*)(&wlds[(j + 1) & 1][wave * 4 + i][0] + lane * 4) = wstage[i];
            #pragma unroll
            for (int r = 0; r < 2; ++r) cur[r] = nxt[r];
        }
        __syncthreads();
    }

    // halving butterfly: 32 slots -> 1 slot/lane within each 32-lane group
    // (same pairing order m=1,2,4,8,16 as the verified 64-slot pattern)
    #pragma unroll
    for (int step = 0; step < 5; ++step) {
        const int m    = 1 << step;
        const int half = 16 >> step;            // 16,8,4,2,1
        const bool hi  = (lane & m) != 0;
        #pragma unroll
        for (int jj = 0; jj < half; ++jj) {
            float send = hi ? acc[jj] : acc[jj + half];
            float recv = __shfl_xor(send, m, 64);
            acc[jj] = (hi ? acc[jj + half] : acc[jj]) + recv;
        }
    }
    // combine the two 32-lane groups (this was step m=32 in the old kernel)
    acc[0] += __shfl_xor(acc[0], 32, 64);

    if (lane < 32) {
        const int slot = ((lane & 1) << 4) | (((lane >> 1) & 1) << 3) | (((lane >> 2) & 1) << 2)
                       | (((lane >> 3) & 1) << 1) | ((lane >> 4) & 1);   // bitrev5
        const int r = slot >> 4, e = slot & 15;
        aff[(size_t)(tbase + r) * N_EXP + e] = acc[0];
    }
}

// ---------------- Kernel 2: bias + softmax + preference lists ----------------
__global__ __launch_bounds__(256) void finalize_kernel(
    const float* __restrict__ aff_in, const float* __restrict__ bias,
    unsigned long long* __restrict__ pref, float* __restrict__ probs)
{
    const int t = blockIdx.x * 256 + threadIdx.x;

    float aff[N_EXP];
    const float4* p = (const float4*)(aff_in + (size_t)t * N_EXP);
    #pragma unroll
    for (int q = 0; q < 4; ++q) {
        float4 v = p[q];
        aff[q*4+0] = v.x; aff[q*4+1] = v.y; aff[q*4+2] = v.z; aff[q*4+3] = v.w;
    }
    #pragma unroll
    for (int e = 0; e < N_EXP; ++e) aff[e] += bias[e];

    float m = aff[0];
    #pragma unroll
    for (int e = 1; e < N_EXP; ++e) m = fmaxf(m, aff[e]);
    float s = 0.f;
    #pragma unroll
    for (int e = 0; e < N_EXP; ++e) s += __expf(aff[e] - m);

    float4* pr = (float4*)(probs + (size_t)t * N_EXP);
    #pragma unroll
    for (int q = 0; q < 4; ++q) {
        float4 v;
        v.x = __expf(aff[q*4+0] - m) / s;
        v.y = __expf(aff[q*4+1] - m) / s;
        v.z = __expf(aff[q*4+2] - m) / s;
        v.w = __expf(aff[q*4+3] - m) / s;
        pr[q] = v;
    }

    unsigned long long key[N_EXP];
    #pragma unroll
    for (int j = 0; j < N_EXP; ++j)
        key[j] = ((unsigned long long)f2ord(aff[j]) << 4) | (unsigned long long)(15 - j);
    unsigned long long pk = 0ull;
    unsigned int used = 0;
    for (int r = 0; r < N_EXP; ++r) {
        unsigned long long bk = 0ull; int be = 0;
        for (int j = 0; j < N_EXP; ++j)
            if (!((used >> j) & 1u) && key[j] > bk) { bk = key[j]; be = j; }
        used |= (1u << be);
        pk = (pk << 4) | (unsigned long long)be;
    }
    pref[t] = pk;
}

// ---------------- Kernel 3: fill-event schedule via segment bitmasks (1 block) ----------------
__global__ __launch_bounds__(512) void events_kernel(
    const unsigned long long* __restrict__ pref, int* __restrict__ evt)
{
    __shared__ unsigned long long prefL[T_TOK];            // 64 KB
    __shared__ unsigned long long segmask[N_EXP][NSEG + 1];// 16.5 KB, [e][s]
    __shared__ int pseg[N_EXP][NSEG + 1];
    __shared__ int rem_cap[N_EXP], fparr[N_EXP];
    __shared__ int s_avail, s_pmin, s_fe, s_seglo;
    __shared__ int evp[N_EXP], evf[N_EXP];

    const int tid  = threadIdx.x;
    const int wave = tid >> 6, lane = tid & 63;
    const unsigned long long lt_mask = (1ull << lane) - 1ull;

    for (int i = tid; i < T_TOK; i += 512) prefL[i] = pref[i];
    if (tid < N_EXP) rem_cap[tid] = CAP;
    if (tid == 0) { s_avail = 0xFFFF; s_seglo = 0; }
    __syncthreads();

    // initial masks from top-nibble choice
    for (int s = wave; s < NSEG; s += 8) {
        int c = (int)(prefL[s * 64 + lane] >> 60);
        #pragma unroll
        for (int e = 0; e < N_EXP; ++e) {
            unsigned long long mm = __ballot(c == e);
            if (lane == e) segmask[e][s] = mm;
        }
    }
    __syncthreads();

    for (int round = 0; round < N_EXP; ++round) {
        const unsigned int avail = (unsigned int)s_avail;

        // A: counts from popc, prefix scan, crossing locate (wave owns e=wave, wave+8)
        #pragma unroll
        for (int ee = 0; ee < 2; ++ee) {
            const int e = wave + ee * 8;
            const unsigned long long m0 = segmask[e][lane];
            const unsigned long long m1 = segmask[e][64 + lane];
            const int c0 = (int)__popcll(m0), c1 = (int)__popcll(m1);
            int v0 = c0;
            #pragma unroll
            for (int d = 1; d < 64; d <<= 1) {
                int o = __shfl_up(v0, d, 64);
                if (lane >= d) v0 += o;
            }
            const int excl0 = v0 - c0;
            const int tot0  = __shfl(v0, 63, 64);
            int v1 = c1;
            #pragma unroll
            for (int d = 1; d < 64; d <<= 1) {
                int o = __shfl_up(v1, d, 64);
                if (lane >= d) v1 += o;
            }
            const int excl1 = tot0 + v1 - c1;
            pseg[e][lane]      = excl0;
            pseg[e][64 + lane] = excl1;

            int fp = 0x7FFFFFFF;
            if ((avail >> e) & 1u) {
                const int need = rem_cap[e];
                int segc = -1, kk = 0;
                if (excl0 < need && excl0 + c0 >= need)      { segc = lane;      kk = need - excl0; }
                else if (excl1 < need && excl1 + c1 >= need) { segc = 64 + lane; kk = need - excl1; }
                unsigned long long b = __ballot(segc >= 0);
                if (b) {
                    int l2    = __builtin_ctzll(b);
                    int sstar = __shfl(segc, l2, 64);
                    int k2    = __shfl(kk,   l2, 64);
                    unsigned long long m = segmask[e][sstar];
                    int rr = (int)__popcll(m & lt_mask);
                    bool hit = ((m >> lane) & 1ull) && (rr == k2 - 1);
                    unsigned long long hb = __ballot(hit);
                    fp = sstar * 64 + __builtin_ctzll(hb);
                }
            }
            if (lane == 0) fparr[e] = fp;
        }
        __syncthreads();

        // B: earliest fill event
        if (tid == 0) {
            int pm = 0x7FFFFFFF, f = 0;
            #pragma unroll
            for (int e = 0; e < N_EXP; ++e)
                if (fparr[e] < pm) { pm = fparr[e]; f = e; }
            s_pmin = pm; s_fe = f;
        }
        __syncthreads();
        const int pmin = s_pmin, fe = s_fe;
        const int segF = pmin >> 6;
        const int seglo = s_seglo;

        // C: capacity update + prune finalized bits
        if (tid < N_EXP) {
            const int e = tid;
            unsigned long long mlep = ((pmin & 63) == 63) ? ~0ull
                                      : ((1ull << ((pmin & 63) + 1)) - 1ull);
            unsigned long long m = segmask[e][segF];
            rem_cap[e] -= pseg[e][segF] + (int)__popcll(m & mlep);
            segmask[e][segF] = m & ~mlep;
        }
        for (int i = tid; i < (segF - seglo) * N_EXP; i += 512)
            segmask[i & 15][seglo + (i >> 4)] = 0ull;
        if (tid == 0) {
            evp[round] = pmin; evf[round] = fe;
            s_avail = (int)(avail & ~(1u << fe));
            s_seglo = segF;
        }
        __syncthreads();

        // D: rewalk only tokens whose choice was fe (set bits of segmask[fe][*])
        if (round < N_EXP - 1) {
            const unsigned int navail = avail & ~(1u << fe);
            for (int s = segF + wave; s < NSEG; s += 8) {
                unsigned long long m = segmask[fe][s];
                if (m) {
                    if ((m >> lane) & 1ull) {
                        unsigned long long pp = prefL[s * 64 + lane];
                        int e2 = (int)(pp >> 60);
                        while (!((navail >> e2) & 1u)) { pp <<= 4; e2 = (int)(pp >> 60); }
                        atomicOr(&segmask[e2][s], 1ull << lane);
                    }
                    if (lane == 0) segmask[fe][s] = 0ull;
                }
            }
        }
        __syncthreads();
    }

    if (tid < N_EXP) { evt[tid] = evp[tid]; evt[N_EXP + tid] = evf[tid]; }
}

// ---------------- Kernel 4: final choice per token + per-block expert counts ----------------
__global__ __launch_bounds__(256) void choice_kernel(
    const unsigned long long* __restrict__ pref, const int* __restrict__ evt,
    unsigned char* __restrict__ t2e, int* __restrict__ bcnt)
{
    __shared__ int evp[N_EXP], evf[N_EXP];
    __shared__ int sc[4][N_EXP];
    const int tid = threadIdx.x, b = blockIdx.x;
    const int wave = tid >> 6, lane = tid & 63;
    if (tid < N_EXP) evp[tid] = evt[tid];
    else if (tid < 2 * N_EXP) evf[tid - N_EXP] = evt[tid];
    __syncthreads();

    const int t = b * 256 + tid;
    unsigned int mask = 0xFFFFu;
    #pragma unroll
    for (int j = 0; j < N_EXP; ++j)
        if (evp[j] < t) mask &= ~(1u << evf[j]);

    unsigned long long pp = pref[t];
    int e = (int)(pp >> 60);
    while (!((mask >> e) & 1u)) { pp <<= 4; e = (int)(pp >> 60); }
    t2e[t] = (unsigned char)e;

    #pragma unroll
    for (int e2 = 0; e2 < N_EXP; ++e2) {
        unsigned long long mm = __ballot(e == e2);
        if (lane == e2) sc[wave][e2] = (int)__popcll(mm);
    }
    __syncthreads();
    if (tid < N_EXP)
        bcnt[b * N_EXP + tid] = sc[0][tid] + sc[1][tid] + sc[2][tid] + sc[3][tid];
}

// ---------------- Kernel 5: ranks + write out0/out1 ----------------
__global__ __launch_bounds__(256) void writeout_kernel(
    const unsigned char* __restrict__ t2e, const int* __restrict__ bcnt,
    const float* __restrict__ probs,
    float* __restrict__ out0, float* __restrict__ out1)
{
    __shared__ int base[N_EXP];
    __shared__ int sc[4][N_EXP];
    const int tid = threadIdx.x, b = blockIdx.x;
    const int wave = tid >> 6, lane = tid & 63;
    const unsigned long long lt_mask = (1ull << lane) - 1ull;

    const int t = b * 256 + tid;
    const int c = (int)t2e[t];

    unsigned long long own = 0ull;
    #pragma unroll
    for (int e2 = 0; e2 < N_EXP; ++e2) {
        unsigned long long mm = __ballot(c == e2);
        if (c == e2) own = mm;
        if (lane == e2) sc[wave][e2] = (int)__popcll(mm);
    }
    if (tid < N_EXP) {
        int s = 0;
        for (int b2 = 0; b2 < b; ++b2) s += bcnt[b2 * N_EXP + tid];
        base[tid] = s;
    }
    __syncthreads();

    int rank = (int)__popcll(own & lt_mask);
    for (int w2 = 0; w2 < wave; ++w2) rank += sc[w2][c];
    const int pos = base[c] + rank;
    out0[c * CAP + pos] = (float)t;
    out1[t] = probs[(size_t)t * N_EXP + c];
}

extern "C" void kernel_launch(void* const* d_in, const int* in_sizes, int n_in,
                              void* d_out, int out_size, void* d_ws, size_t ws_size,
                              hipStream_t stream) {
    const float* feat = (const float*)d_in[0];
    const float* W    = (const float*)d_in[1];
    const float* bias = (const float*)d_in[2];

    float* out = (float*)d_out;
    char*  ws  = (char*)d_ws;

    float* aff               = (float*)ws;
    unsigned long long* pref = (unsigned long long*)(ws + 524288);
    float* probs             = (float*)(ws + 589824);
    int* evt                 = (int*)(ws + 1114112);
    unsigned char* t2e       = (unsigned char*)(ws + 1114240);
    int* bcnt                = (int*)(ws + 1122432);

    hipLaunchKernelGGL(gemm_aff_kernel, dim3(1024), dim3(256), 0, stream,
                       feat, W, aff);
    hipLaunchKernelGGL(finalize_kernel, dim3(T_TOK / 256), dim3(256), 0, stream,
                       aff, bias, pref, probs);
    hipLaunchKernelGGL(events_kernel, dim3(1), dim3(512), 0, stream,
                       pref, evt);
    hipLaunchKernelGGL(choice_kernel, dim3(T_TOK / 256), dim3(256), 0, stream,
                       pref, evt, t2e, bcnt);
    hipLaunchKernelGGL(writeout_kernel, dim3(T_TOK / 256), dim3(256), 0, stream,
                       t2e, bcnt, probs, out, out + T_TOK);
}

// Round 2
// 187.682 us; speedup vs baseline: 1.6644x; 1.6644x over previous
//
#include <hip/hip_runtime.h>
#include <hip/hip_bf16.h>
#include <math.h>

#define T_TOK 8192
#define D_MODEL 2048
#define N_EXP 16
#define CAP 512
#define NSEG (T_TOK / 64)           // 128

// ws layout (bytes):
// aff:   0       .. 524288    float[T_TOK][16]
// pref:  524288  .. +65536    u64[T_TOK]
// probs: 589824  .. +524288   float[T_TOK][16]
// evt:   1114112 .. +128      int[32] (evp[16], evf[16])
// t2e:   1114240 .. +8192     u8[T_TOK]
// bcnt:  1122432 .. +2048     int[32][16]

__device__ __forceinline__ unsigned int f2ord(float f) {
    unsigned int b = __float_as_uint(f);
    return (b & 0x80000000u) ? ~b : (b | 0x80000000u);
}

// ---------------- Kernel 1: GEMM, feat staged in LDS once, acc[16]/lane (no spill) ----------------
// 1024 blocks x 512 thr (8 waves). Block owns 8 tokens; feat tile (64 KiB) staged to LDS once.
// Wave owns 2 experts (e = wave*2, wave*2+1); lane slices K (floats j*256 + lane*4, j=0..7).
// acc[16] = 8 tokens x 2 experts -> fits the 64-VGPR allocation the compiler favors; no scratch.
// Numerics bit-identical to the verified r0 kernel: same per-lane K slices, same j/component
// FMA order, same lane-pair merge order (m=1,2,4,8 butterfly, then m=16, m=32).
__global__ __launch_bounds__(512, 4) void gemm_aff_kernel(
    const float* __restrict__ feat, const float* __restrict__ W,
    float* __restrict__ aff)
{
    __shared__ float flds[8][D_MODEL];   // 64 KiB

    const int tid  = threadIdx.x;
    const int wave = tid >> 6, lane = tid & 63;
    const int tbase = blockIdx.x * 8;

    // stage feat tile: 4096 float4s, 512 threads x 8, fully coalesced
    {
        const float4* src = (const float4*)(feat + (size_t)tbase * D_MODEL);
        float4* dst = (float4*)&flds[0][0];
        #pragma unroll
        for (int i = 0; i < 8; ++i)
            dst[tid + i * 512] = src[tid + i * 512];
    }

    // this wave's two expert rows, this lane's K-slice base
    const float* w0 = W + (size_t)(wave * 2) * D_MODEL + lane * 4;
    const float* w1 = w0 + D_MODEL;

    float acc[16];   // acc[r*2 + el], r = token 0..7, el = expert-local 0..1
    #pragma unroll
    for (int i = 0; i < 16; ++i) acc[i] = 0.f;

    // prefetch W chunk 0 (independent of LDS) before the barrier
    float4 wv0 = *(const float4*)(w0);
    float4 wv1 = *(const float4*)(w1);
    __syncthreads();

    #pragma unroll
    for (int j = 0; j < 8; ++j) {               // 8 k-chunks of 256 floats
        float4 wn0, wn1;
        if (j < 7) {
            wn0 = *(const float4*)(w0 + (j + 1) * 256);
            wn1 = *(const float4*)(w1 + (j + 1) * 256);
        } else {
            wn0 = wv0; wn1 = wv1;
        }
        const float* fl = &flds[0][0] + j * 256 + lane * 4;
        #pragma unroll
        for (int r = 0; r < 8; ++r) {
            float4 f = *(const float4*)(fl + r * D_MODEL);
            acc[r * 2 + 0] += f.x * wv0.x;
            acc[r * 2 + 0] += f.y * wv0.y;
            acc[r * 2 + 0] += f.z * wv0.z;
            acc[r * 2 + 0] += f.w * wv0.w;
            acc[r * 2 + 1] += f.x * wv1.x;
            acc[r * 2 + 1] += f.y * wv1.y;
            acc[r * 2 + 1] += f.z * wv1.z;
            acc[r * 2 + 1] += f.w * wv1.w;
        }
        wv0 = wn0; wv1 = wn1;
    }

    // halving butterfly: 16 slots -> 1 slot/lane over lane bits 0..3
    // (same pairing order m=1,2,4,8 as the verified 64-slot pattern)
    #pragma unroll
    for (int step = 0; step < 4; ++step) {
        const int m    = 1 << step;
        const int half = 8 >> step;             // 8,4,2,1
        const bool hi  = (lane & m) != 0;
        #pragma unroll
        for (int jj = 0; jj < half; ++jj) {
            float send = hi ? acc[jj] : acc[jj + half];
            float recv = __shfl_xor(send, m, 64);
            acc[jj] = (hi ? acc[jj + half] : acc[jj]) + recv;
        }
    }
    // finish lane reduction over bits 4,5 (same merge order as r0's m=16, m=32 steps)
    acc[0] += __shfl_xor(acc[0], 16, 64);
    acc[0] += __shfl_xor(acc[0], 32, 64);

    if (lane < 16) {
        const int slot = ((lane & 1) << 3) | (((lane >> 1) & 1) << 2)
                       | (((lane >> 2) & 1) << 1) | ((lane >> 3) & 1);   // bitrev4
        const int r = slot >> 1, el = slot & 1;
        aff[(size_t)(tbase + r) * N_EXP + wave * 2 + el] = acc[0];
    }
}

// ---------------- Kernel 2: bias + softmax + preference lists ----------------
__global__ __launch_bounds__(256) void finalize_kernel(
    const float* __restrict__ aff_in, const float* __restrict__ bias,
    unsigned long long* __restrict__ pref, float* __restrict__ probs)
{
    const int t = blockIdx.x * 256 + threadIdx.x;

    float aff[N_EXP];
    const float4* p = (const float4*)(aff_in + (size_t)t * N_EXP);
    #pragma unroll
    for (int q = 0; q < 4; ++q) {
        float4 v = p[q];
        aff[q*4+0] = v.x; aff[q*4+1] = v.y; aff[q*4+2] = v.z; aff[q*4+3] = v.w;
    }
    #pragma unroll
    for (int e = 0; e < N_EXP; ++e) aff[e] += bias[e];

    float m = aff[0];
    #pragma unroll
    for (int e = 1; e < N_EXP; ++e) m = fmaxf(m, aff[e]);
    float s = 0.f;
    #pragma unroll
    for (int e = 0; e < N_EXP; ++e) s += __expf(aff[e] - m);

    float4* pr = (float4*)(probs + (size_t)t * N_EXP);
    #pragma unroll
    for (int q = 0; q < 4; ++q) {
        float4 v;
        v.x = __expf(aff[q*4+0] - m) / s;
        v.y = __expf(aff[q*4+1] - m) / s;
        v.z = __expf(aff[q*4+2] - m) / s;
        v.w = __expf(aff[q*4+3] - m) / s;
        pr[q] = v;
    }

    unsigned long long key[N_EXP];
    #pragma unroll
    for (int j = 0; j < N_EXP; ++j)
        key[j] = ((unsigned long long)f2ord(aff[j]) << 4) | (unsigned long long)(15 - j);
    unsigned long long pk = 0ull;
    unsigned int used = 0;
    for (int r = 0; r < N_EXP; ++r) {
        unsigned long long bk = 0ull; int be = 0;
        for (int j = 0; j < N_EXP; ++j)
            if (!((used >> j) & 1u) && key[j] > bk) { bk = key[j]; be = j; }
        used |= (1u << be);
        pk = (pk << 4) | (unsigned long long)be;
    }
    pref[t] = pk;
}

// ---------------- Kernel 3: fill-event schedule via segment bitmasks (1 block) ----------------
__global__ __launch_bounds__(512) void events_kernel(
    const unsigned long long* __restrict__ pref, int* __restrict__ evt)
{
    __shared__ unsigned long long prefL[T_TOK];            // 64 KB
    __shared__ unsigned long long segmask[N_EXP][NSEG + 1];// 16.5 KB, [e][s]
    __shared__ int pseg[N_EXP][NSEG + 1];
    __shared__ int rem_cap[N_EXP], fparr[N_EXP];
    __shared__ int s_avail, s_pmin, s_fe, s_seglo;
    __shared__ int evp[N_EXP], evf[N_EXP];

    const int tid  = threadIdx.x;
    const int wave = tid >> 6, lane = tid & 63;
    const unsigned long long lt_mask = (1ull << lane) - 1ull;

    for (int i = tid; i < T_TOK; i += 512) prefL[i] = pref[i];
    if (tid < N_EXP) rem_cap[tid] = CAP;
    if (tid == 0) { s_avail = 0xFFFF; s_seglo = 0; }
    __syncthreads();

    // initial masks from top-nibble choice
    for (int s = wave; s < NSEG; s += 8) {
        int c = (int)(prefL[s * 64 + lane] >> 60);
        #pragma unroll
        for (int e = 0; e < N_EXP; ++e) {
            unsigned long long mm = __ballot(c == e);
            if (lane == e) segmask[e][s] = mm;
        }
    }
    __syncthreads();

    for (int round = 0; round < N_EXP; ++round) {
        const unsigned int avail = (unsigned int)s_avail;

        // A: counts from popc, prefix scan, crossing locate (wave owns e=wave, wave+8)
        #pragma unroll
        for (int ee = 0; ee < 2; ++ee) {
            const int e = wave + ee * 8;
            const unsigned long long m0 = segmask[e][lane];
            const unsigned long long m1 = segmask[e][64 + lane];
            const int c0 = (int)__popcll(m0), c1 = (int)__popcll(m1);
            int v0 = c0;
            #pragma unroll
            for (int d = 1; d < 64; d <<= 1) {
                int o = __shfl_up(v0, d, 64);
                if (lane >= d) v0 += o;
            }
            const int excl0 = v0 - c0;
            const int tot0  = __shfl(v0, 63, 64);
            int v1 = c1;
            #pragma unroll
            for (int d = 1; d < 64; d <<= 1) {
                int o = __shfl_up(v1, d, 64);
                if (lane >= d) v1 += o;
            }
            const int excl1 = tot0 + v1 - c1;
            pseg[e][lane]      = excl0;
            pseg[e][64 + lane] = excl1;

            int fp = 0x7FFFFFFF;
            if ((avail >> e) & 1u) {
                const int need = rem_cap[e];
                int segc = -1, kk = 0;
                if (excl0 < need && excl0 + c0 >= need)      { segc = lane;      kk = need - excl0; }
                else if (excl1 < need && excl1 + c1 >= need) { segc = 64 + lane; kk = need - excl1; }
                unsigned long long b = __ballot(segc >= 0);
                if (b) {
                    int l2    = __builtin_ctzll(b);
                    int sstar = __shfl(segc, l2, 64);
                    int k2    = __shfl(kk,   l2, 64);
                    unsigned long long m = segmask[e][sstar];
                    int rr = (int)__popcll(m & lt_mask);
                    bool hit = ((m >> lane) & 1ull) && (rr == k2 - 1);
                    unsigned long long hb = __ballot(hit);
                    fp = sstar * 64 + __builtin_ctzll(hb);
                }
            }
            if (lane == 0) fparr[e] = fp;
        }
        __syncthreads();

        // B: earliest fill event
        if (tid == 0) {
            int pm = 0x7FFFFFFF, f = 0;
            #pragma unroll
            for (int e = 0; e < N_EXP; ++e)
                if (fparr[e] < pm) { pm = fparr[e]; f = e; }
            s_pmin = pm; s_fe = f;
        }
        __syncthreads();
        const int pmin = s_pmin, fe = s_fe;
        const int segF = pmin >> 6;
        const int seglo = s_seglo;

        // C: capacity update + prune finalized bits
        if (tid < N_EXP) {
            const int e = tid;
            unsigned long long mlep = ((pmin & 63) == 63) ? ~0ull
                                      : ((1ull << ((pmin & 63) + 1)) - 1ull);
            unsigned long long m = segmask[e][segF];
            rem_cap[e] -= pseg[e][segF] + (int)__popcll(m & mlep);
            segmask[e][segF] = m & ~mlep;
        }
        for (int i = tid; i < (segF - seglo) * N_EXP; i += 512)
            segmask[i & 15][seglo + (i >> 4)] = 0ull;
        if (tid == 0) {
            evp[round] = pmin; evf[round] = fe;
            s_avail = (int)(avail & ~(1u << fe));
            s_seglo = segF;
        }
        __syncthreads();

        // D: rewalk only tokens whose choice was fe (set bits of segmask[fe][*])
        if (round < N_EXP - 1) {
            const unsigned int navail = avail & ~(1u << fe);
            for (int s = segF + wave; s < NSEG; s += 8) {
                unsigned long long m = segmask[fe][s];
                if (m) {
                    if ((m >> lane) & 1ull) {
                        unsigned long long pp = prefL[s * 64 + lane];
                        int e2 = (int)(pp >> 60);
                        while (!((navail >> e2) & 1u)) { pp <<= 4; e2 = (int)(pp >> 60); }
                        atomicOr(&segmask[e2][s], 1ull << lane);
                    }
                    if (lane == 0) segmask[fe][s] = 0ull;
                }
            }
        }
        __syncthreads();
    }

    if (tid < N_EXP) { evt[tid] = evp[tid]; evt[N_EXP + tid] = evf[tid]; }
}

// ---------------- Kernel 4: final choice per token + per-block expert counts ----------------
__global__ __launch_bounds__(256) void choice_kernel(
    const unsigned long long* __restrict__ pref, const int* __restrict__ evt,
    unsigned char* __restrict__ t2e, int* __restrict__ bcnt)
{
    __shared__ int evp[N_EXP], evf[N_EXP];
    __shared__ int sc[4][N_EXP];
    const int tid = threadIdx.x, b = blockIdx.x;
    const int wave = tid >> 6, lane = tid & 63;
    if (tid < N_EXP) evp[tid] = evt[tid];
    else if (tid < 2 * N_EXP) evf[tid - N_EXP] = evt[tid];
    __syncthreads();

    const int t = b * 256 + tid;
    unsigned int mask = 0xFFFFu;
    #pragma unroll
    for (int j = 0; j < N_EXP; ++j)
        if (evp[j] < t) mask &= ~(1u << evf[j]);

    unsigned long long pp = pref[t];
    int e = (int)(pp >> 60);
    while (!((mask >> e) & 1u)) { pp <<= 4; e = (int)(pp >> 60); }
    t2e[t] = (unsigned char)e;

    #pragma unroll
    for (int e2 = 0; e2 < N_EXP; ++e2) {
        unsigned long long mm = __ballot(e == e2);
        if (lane == e2) sc[wave][e2] = (int)__popcll(mm);
    }
    __syncthreads();
    if (tid < N_EXP)
        bcnt[b * N_EXP + tid] = sc[0][tid] + sc[1][tid] + sc[2][tid] + sc[3][tid];
}

// ---------------- Kernel 5: ranks + write out0/out1 ----------------
__global__ __launch_bounds__(256) void writeout_kernel(
    const unsigned char* __restrict__ t2e, const int* __restrict__ bcnt,
    const float* __restrict__ probs,
    float* __restrict__ out0, float* __restrict__ out1)
{
    __shared__ int base[N_EXP];
    __shared__ int sc[4][N_EXP];
    const int tid = threadIdx.x, b = blockIdx.x;
    const int wave = tid >> 6, lane = tid & 63;
    const unsigned long long lt_mask = (1ull << lane) - 1ull;

    const int t = b * 256 + tid;
    const int c = (int)t2e[t];

    unsigned long long own = 0ull;
    #pragma unroll
    for (int e2 = 0; e2 < N_EXP; ++e2) {
        unsigned long long mm = __ballot(c == e2);
        if (c == e2) own = mm;
        if (lane == e2) sc[wave][e2] = (int)__popcll(mm);
    }
    if (tid < N_EXP) {
        int s = 0;
        for (int b2 = 0; b2 < b; ++b2) s += bcnt[b2 * N_EXP + tid];
        base[tid] = s;
    }
    __syncthreads();

    int rank = (int)__popcll(own & lt_mask);
    for (int w2 = 0; w2 < wave; ++w2) rank += sc[w2][c];
    const int pos = base[c] + rank;
    out0[c * CAP + pos] = (float)t;
    out1[t] = probs[(size_t)t * N_EXP + c];
}

extern "C" void kernel_launch(void* const* d_in, const int* in_sizes, int n_in,
                              void* d_out, int out_size, void* d_ws, size_t ws_size,
                              hipStream_t stream) {
    const float* feat = (const float*)d_in[0];
    const float* W    = (const float*)d_in[1];
    const float* bias = (const float*)d_in[2];

    float* out = (float*)d_out;
    char*  ws  = (char*)d_ws;

    float* aff               = (float*)ws;
    unsigned long long* pref = (unsigned long long*)(ws + 524288);
    float* probs             = (float*)(ws + 589824);
    int* evt                 = (int*)(ws + 1114112);
    unsigned char* t2e       = (unsigned char*)(ws + 1114240);
    int* bcnt                = (int*)(ws + 1122432);

    hipLaunchKernelGGL(gemm_aff_kernel, dim3(T_TOK / 8), dim3(512), 0, stream,
                       feat, W, aff);
    hipLaunchKernelGGL(finalize_kernel, dim3(T_TOK / 256), dim3(256), 0, stream,
                       aff, bias, pref, probs);
    hipLaunchKernelGGL(events_kernel, dim3(1), dim3(512), 0, stream,
                       pref, evt);
    hipLaunchKernelGGL(choice_kernel, dim3(T_TOK / 256), dim3(256), 0, stream,
                       pref, evt, t2e, bcnt);
    hipLaunchKernelGGL(writeout_kernel, dim3(T_TOK / 256), dim3(256), 0, stream,
                       t2e, bcnt, probs, out, out + T_TOK);
}

// Round 3
// 185.639 us; speedup vs baseline: 1.6827x; 1.0110x over previous
//
#include <hip/hip_runtime.h>
#include <hip/hip_bf16.h>
#include <math.h>

#define T_TOK 8192
#define D_MODEL 2048
#define N_EXP 16
#define CAP 512
#define NSEG (T_TOK / 64)           // 128

// ws layout (bytes):
// aff:   0       .. 524288    float[T_TOK][16]
// pref:  524288  .. +65536    u64[T_TOK]
// probs: 589824  .. +524288   float[T_TOK][16]
// evt:   1114112 .. +128      int[32] (evp[16], evf[16])
// t2e:   1114240 .. +8192     u8[T_TOK]
// bcnt:  1122432 .. +2048     int[32][16]

__device__ __forceinline__ unsigned int f2ord(float f) {
    unsigned int b = __float_as_uint(f);
    return (b & 0x80000000u) ? ~b : (b | 0x80000000u);
}

// ---------------- Kernel 1: GEMM, feat staged in LDS once, acc[16]/lane (no spill) ----------------
// (unchanged from r2 — verified, no longer in the top-5 profile)
__global__ __launch_bounds__(512, 4) void gemm_aff_kernel(
    const float* __restrict__ feat, const float* __restrict__ W,
    float* __restrict__ aff)
{
    __shared__ float flds[8][D_MODEL];   // 64 KiB

    const int tid  = threadIdx.x;
    const int wave = tid >> 6, lane = tid & 63;
    const int tbase = blockIdx.x * 8;

    {
        const float4* src = (const float4*)(feat + (size_t)tbase * D_MODEL);
        float4* dst = (float4*)&flds[0][0];
        #pragma unroll
        for (int i = 0; i < 8; ++i)
            dst[tid + i * 512] = src[tid + i * 512];
    }

    const float* w0 = W + (size_t)(wave * 2) * D_MODEL + lane * 4;
    const float* w1 = w0 + D_MODEL;

    float acc[16];
    #pragma unroll
    for (int i = 0; i < 16; ++i) acc[i] = 0.f;

    float4 wv0 = *(const float4*)(w0);
    float4 wv1 = *(const float4*)(w1);
    __syncthreads();

    #pragma unroll
    for (int j = 0; j < 8; ++j) {
        float4 wn0, wn1;
        if (j < 7) {
            wn0 = *(const float4*)(w0 + (j + 1) * 256);
            wn1 = *(const float4*)(w1 + (j + 1) * 256);
        } else {
            wn0 = wv0; wn1 = wv1;
        }
        const float* fl = &flds[0][0] + j * 256 + lane * 4;
        #pragma unroll
        for (int r = 0; r < 8; ++r) {
            float4 f = *(const float4*)(fl + r * D_MODEL);
            acc[r * 2 + 0] += f.x * wv0.x;
            acc[r * 2 + 0] += f.y * wv0.y;
            acc[r * 2 + 0] += f.z * wv0.z;
            acc[r * 2 + 0] += f.w * wv0.w;
            acc[r * 2 + 1] += f.x * wv1.x;
            acc[r * 2 + 1] += f.y * wv1.y;
            acc[r * 2 + 1] += f.z * wv1.z;
            acc[r * 2 + 1] += f.w * wv1.w;
        }
        wv0 = wn0; wv1 = wn1;
    }

    #pragma unroll
    for (int step = 0; step < 4; ++step) {
        const int m    = 1 << step;
        const int half = 8 >> step;
        const bool hi  = (lane & m) != 0;
        #pragma unroll
        for (int jj = 0; jj < half; ++jj) {
            float send = hi ? acc[jj] : acc[jj + half];
            float recv = __shfl_xor(send, m, 64);
            acc[jj] = (hi ? acc[jj + half] : acc[jj]) + recv;
        }
    }
    acc[0] += __shfl_xor(acc[0], 16, 64);
    acc[0] += __shfl_xor(acc[0], 32, 64);

    if (lane < 16) {
        const int slot = ((lane & 1) << 3) | (((lane >> 1) & 1) << 2)
                       | (((lane >> 2) & 1) << 1) | ((lane >> 3) & 1);
        const int r = slot >> 1, el = slot & 1;
        aff[(size_t)(tbase + r) * N_EXP + wave * 2 + el] = acc[0];
    }
}

// ---------------- Kernel 2: bias + softmax + preference lists ----------------
__global__ __launch_bounds__(256) void finalize_kernel(
    const float* __restrict__ aff_in, const float* __restrict__ bias,
    unsigned long long* __restrict__ pref, float* __restrict__ probs)
{
    const int t = blockIdx.x * 256 + threadIdx.x;

    float aff[N_EXP];
    const float4* p = (const float4*)(aff_in + (size_t)t * N_EXP);
    #pragma unroll
    for (int q = 0; q < 4; ++q) {
        float4 v = p[q];
        aff[q*4+0] = v.x; aff[q*4+1] = v.y; aff[q*4+2] = v.z; aff[q*4+3] = v.w;
    }
    #pragma unroll
    for (int e = 0; e < N_EXP; ++e) aff[e] += bias[e];

    float m = aff[0];
    #pragma unroll
    for (int e = 1; e < N_EXP; ++e) m = fmaxf(m, aff[e]);
    float s = 0.f;
    #pragma unroll
    for (int e = 0; e < N_EXP; ++e) s += __expf(aff[e] - m);

    float4* pr = (float4*)(probs + (size_t)t * N_EXP);
    #pragma unroll
    for (int q = 0; q < 4; ++q) {
        float4 v;
        v.x = __expf(aff[q*4+0] - m) / s;
        v.y = __expf(aff[q*4+1] - m) / s;
        v.z = __expf(aff[q*4+2] - m) / s;
        v.w = __expf(aff[q*4+3] - m) / s;
        pr[q] = v;
    }

    unsigned long long key[N_EXP];
    #pragma unroll
    for (int j = 0; j < N_EXP; ++j)
        key[j] = ((unsigned long long)f2ord(aff[j]) << 4) | (unsigned long long)(15 - j);
    unsigned long long pk = 0ull;
    unsigned int used = 0;
    for (int r = 0; r < N_EXP; ++r) {
        unsigned long long bk = 0ull; int be = 0;
        for (int j = 0; j < N_EXP; ++j)
            if (!((used >> j) & 1u) && key[j] > bk) { bk = key[j]; be = j; }
        used |= (1u << be);
        pk = (pk << 4) | (unsigned long long)be;
    }
    pref[t] = pk;
}

// ---------------- Kernel 3: fill-event schedule, register-resident, 2 barriers/round ----------------
// 1 block x 512 thr. Pref keys live in registers (myPref[k] = pref[tid + 512k], i.e. token
// (8k+wave)*64+lane -> segment 8k+wave, bit = lane). Pruning is lazy/in-register: history of
// all prior rounds' pruning == {segments < segF zeroed, segment segF &= ~mlep} with the LATEST
// (segF, mlep), since pmin strictly increases. Capacity commits use the previous round's scan
// registers via shfl (identical values the old phase C read from pseg/segmask). Value-for-value
// identical evt output to the verified r0-r2 events_kernel.
__global__ __launch_bounds__(512, 1) void events_kernel(
    const unsigned long long* __restrict__ pref, int* __restrict__ evt)
{
    __shared__ unsigned long long segmask[N_EXP][NSEG];   // 16 KB
    __shared__ int fparr[N_EXP];

    const int tid  = threadIdx.x;
    const int wave = tid >> 6, lane = tid & 63;
    const unsigned long long lt_mask = (1ull << lane) - 1ull;

    // pref keys -> registers (coalesced; statically indexed via full unroll)
    unsigned long long myPref[16];
    #pragma unroll
    for (int k = 0; k < 16; ++k) myPref[k] = pref[tid + 512 * k];

    // initial per-expert segment masks from top-nibble choice
    #pragma unroll
    for (int k = 0; k < 16; ++k) {
        const int s = k * 8 + wave;
        const int c = (int)(myPref[k] >> 60);
        #pragma unroll
        for (int e = 0; e < N_EXP; ++e) {
            unsigned long long mm = __ballot(c == e);
            if (lane == e) segmask[e][s] = mm;
        }
    }
    __syncthreads();

    const int eA = wave, eB = wave + 8;
    int capA = CAP, capB = CAP;
    unsigned long long m0A = 0, m1A = 0, m0B = 0, m1B = 0;   // prev-round pruned masks
    int excl0A = 0, excl1A = 0, excl0B = 0, excl1B = 0;      // prev-round excl prefixes
    int segF = 0;                      // prev round's fill segment
    unsigned long long mlep = 0;       // prev round's <=pmin bitmask within segF
    unsigned int avail = 0xFFFFu;
    int myp = 0, myf = 0;

    for (int round = 0; round < N_EXP; ++round) {
        // ---- capacity commit from previous round (no-op at round 0: all regs are 0) ----
        {
            int exf = (segF < 64) ? __shfl(excl0A, segF, 64) : __shfl(excl1A, segF - 64, 64);
            unsigned long long mf = (segF < 64) ? __shfl(m0A, segF, 64) : __shfl(m1A, segF - 64, 64);
            capA -= exf + (int)__popcll(mf & mlep);
            exf = (segF < 64) ? __shfl(excl0B, segF, 64) : __shfl(excl1B, segF - 64, 64);
            mf  = (segF < 64) ? __shfl(m0B, segF, 64) : __shfl(m1B, segF - 64, 64);
            capB -= exf + (int)__popcll(mf & mlep);
        }

        // ---- load masks + lazy in-register prune ----
        unsigned long long a0 = segmask[eA][lane];
        unsigned long long a1 = segmask[eA][64 + lane];
        unsigned long long b0 = segmask[eB][lane];
        unsigned long long b1 = segmask[eB][64 + lane];
        if (lane < segF)            { a0 = 0; b0 = 0; }
        else if (lane == segF)      { a0 &= ~mlep; b0 &= ~mlep; }
        if (64 + lane < segF)       { a1 = 0; b1 = 0; }
        else if (64 + lane == segF) { a1 &= ~mlep; b1 &= ~mlep; }
        m0A = a0; m1A = a1; m0B = b0; m1B = b1;

        // ---- 4 interleaved inclusive scans over 64 segments (ILP) ----
        const int c0A = (int)__popcll(a0), c1A = (int)__popcll(a1);
        const int c0B = (int)__popcll(b0), c1B = (int)__popcll(b1);
        int v0A = c0A, v1A = c1A, v0B = c0B, v1B = c1B;
        #pragma unroll
        for (int d = 1; d < 64; d <<= 1) {
            int t0 = __shfl_up(v0A, d, 64);
            int t1 = __shfl_up(v1A, d, 64);
            int t2 = __shfl_up(v0B, d, 64);
            int t3 = __shfl_up(v1B, d, 64);
            if (lane >= d) { v0A += t0; v1A += t1; v0B += t2; v1B += t3; }
        }
        const int tot0A = __shfl(v0A, 63, 64);
        const int tot0B = __shfl(v0B, 63, 64);
        excl0A = v0A - c0A;
        excl1A = tot0A + v1A - c1A;
        excl0B = v0B - c0B;
        excl1B = tot0B + v1B - c1B;

        // ---- crossing locate (expert A) ----
        int fpA = 0x7FFFFFFF;
        if ((avail >> eA) & 1u) {
            const int need = capA;
            int segc = -1, kk = 0;
            if (excl0A < need && excl0A + c0A >= need)      { segc = lane;      kk = need - excl0A; }
            else if (excl1A < need && excl1A + c1A >= need) { segc = 64 + lane; kk = need - excl1A; }
            unsigned long long bb = __ballot(segc >= 0);
            if (bb) {
                int l2    = __builtin_ctzll(bb);
                int sstar = __shfl(segc, l2, 64);
                int k2    = __shfl(kk,   l2, 64);
                unsigned long long msel = (sstar < 64) ? __shfl(a0, sstar, 64)
                                                       : __shfl(a1, sstar - 64, 64);
                int rr = (int)__popcll(msel & lt_mask);
                bool hit = ((msel >> lane) & 1ull) && (rr == k2 - 1);
                unsigned long long hb = __ballot(hit);
                fpA = sstar * 64 + __builtin_ctzll(hb);
            }
        }
        // ---- crossing locate (expert B) ----
        int fpB = 0x7FFFFFFF;
        if ((avail >> eB) & 1u) {
            const int need = capB;
            int segc = -1, kk = 0;
            if (excl0B < need && excl0B + c0B >= need)      { segc = lane;      kk = need - excl0B; }
            else if (excl1B < need && excl1B + c1B >= need) { segc = 64 + lane; kk = need - excl1B; }
            unsigned long long bb = __ballot(segc >= 0);
            if (bb) {
                int l2    = __builtin_ctzll(bb);
                int sstar = __shfl(segc, l2, 64);
                int k2    = __shfl(kk,   l2, 64);
                unsigned long long msel = (sstar < 64) ? __shfl(b0, sstar, 64)
                                                       : __shfl(b1, sstar - 64, 64);
                int rr = (int)__popcll(msel & lt_mask);
                bool hit = ((msel >> lane) & 1ull) && (rr == k2 - 1);
                unsigned long long hb = __ballot(hit);
                fpB = sstar * 64 + __builtin_ctzll(hb);
            }
        }
        if (lane == 0) { fparr[eA] = fpA; fparr[eB] = fpB; }
        __syncthreads();   // barrier 1

        // ---- all threads redundantly: earliest fill event (same tie-break as tid==0 loop) ----
        int pmin = 0x7FFFFFFF, fe = 0;
        #pragma unroll
        for (int e = 0; e < N_EXP; ++e) {
            int f = fparr[e];
            if (f < pmin) { pmin = f; fe = e; }
        }
        if (tid == round) { myp = pmin; myf = fe; }

        const int nsegF = pmin >> 6;
        const unsigned long long nmlep = ((pmin & 63) == 63) ? ~0ull
                                         : ((1ull << ((pmin & 63) + 1)) - 1ull);
        const unsigned int navail = avail & ~(1u << fe);

        // ---- rewalk fe's tokens at s >= nsegF (register pref, no fe-row zeroing needed) ----
        if (round < N_EXP - 1) {
            #pragma unroll
            for (int k = 0; k < 16; ++k) {
                const int s = k * 8 + wave;
                if (s >= nsegF) {
                    unsigned long long m = segmask[fe][s];
                    if (s == nsegF) m &= ~nmlep;
                    if ((m >> lane) & 1ull) {
                        unsigned long long pp = myPref[k];
                        int e2 = (int)(pp >> 60);
                        while (!((navail >> e2) & 1u)) { pp <<= 4; e2 = (int)(pp >> 60); }
                        atomicOr(&segmask[e2][s], 1ull << lane);
                    }
                }
            }
        }
        segF = nsegF; mlep = nmlep; avail = navail;
        __syncthreads();   // barrier 2
    }

    if (tid < N_EXP) { evt[tid] = myp; evt[N_EXP + tid] = myf; }
}

// ---------------- Kernel 4: final choice per token + per-block expert counts ----------------
__global__ __launch_bounds__(256) void choice_kernel(
    const unsigned long long* __restrict__ pref, const int* __restrict__ evt,
    unsigned char* __restrict__ t2e, int* __restrict__ bcnt)
{
    __shared__ int evp[N_EXP], evf[N_EXP];
    __shared__ int sc[4][N_EXP];
    const int tid = threadIdx.x, b = blockIdx.x;
    const int wave = tid >> 6, lane = tid & 63;
    if (tid < N_EXP) evp[tid] = evt[tid];
    else if (tid < 2 * N_EXP) evf[tid - N_EXP] = evt[tid];
    __syncthreads();

    const int t = b * 256 + tid;
    unsigned int mask = 0xFFFFu;
    #pragma unroll
    for (int j = 0; j < N_EXP; ++j)
        if (evp[j] < t) mask &= ~(1u << evf[j]);

    unsigned long long pp = pref[t];
    int e = (int)(pp >> 60);
    while (!((mask >> e) & 1u)) { pp <<= 4; e = (int)(pp >> 60); }
    t2e[t] = (unsigned char)e;

    #pragma unroll
    for (int e2 = 0; e2 < N_EXP; ++e2) {
        unsigned long long mm = __ballot(e == e2);
        if (lane == e2) sc[wave][e2] = (int)__popcll(mm);
    }
    __syncthreads();
    if (tid < N_EXP)
        bcnt[b * N_EXP + tid] = sc[0][tid] + sc[1][tid] + sc[2][tid] + sc[3][tid];
}

// ---------------- Kernel 5: ranks + write out0/out1 ----------------
__global__ __launch_bounds__(256) void writeout_kernel(
    const unsigned char* __restrict__ t2e, const int* __restrict__ bcnt,
    const float* __restrict__ probs,
    float* __restrict__ out0, float* __restrict__ out1)
{
    __shared__ int base[N_EXP];
    __shared__ int sc[4][N_EXP];
    const int tid = threadIdx.x, b = blockIdx.x;
    const int wave = tid >> 6, lane = tid & 63;
    const unsigned long long lt_mask = (1ull << lane) - 1ull;

    const int t = b * 256 + tid;
    const int c = (int)t2e[t];

    unsigned long long own = 0ull;
    #pragma unroll
    for (int e2 = 0; e2 < N_EXP; ++e2) {
        unsigned long long mm = __ballot(c == e2);
        if (c == e2) own = mm;
        if (lane == e2) sc[wave][e2] = (int)__popcll(mm);
    }
    if (tid < N_EXP) {
        int s = 0;
        for (int b2 = 0; b2 < b; ++b2) s += bcnt[b2 * N_EXP + tid];
        base[tid] = s;
    }
    __syncthreads();

    int rank = (int)__popcll(own & lt_mask);
    for (int w2 = 0; w2 < wave; ++w2) rank += sc[w2][c];
    const int pos = base[c] + rank;
    out0[c * CAP + pos] = (float)t;
    out1[t] = probs[(size_t)t * N_EXP + c];
}

extern "C" void kernel_launch(void* const* d_in, const int* in_sizes, int n_in,
                              void* d_out, int out_size, void* d_ws, size_t ws_size,
                              hipStream_t stream) {
    const float* feat = (const float*)d_in[0];
    const float* W    = (const float*)d_in[1];
    const float* bias = (const float*)d_in[2];

    float* out = (float*)d_out;
    char*  ws  = (char*)d_ws;

    float* aff               = (float*)ws;
    unsigned long long* pref = (unsigned long long*)(ws + 524288);
    float* probs             = (float*)(ws + 589824);
    int* evt                 = (int*)(ws + 1114112);
    unsigned char* t2e       = (unsigned char*)(ws + 1114240);
    int* bcnt                = (int*)(ws + 1122432);

    hipLaunchKernelGGL(gemm_aff_kernel, dim3(T_TOK / 8), dim3(512), 0, stream,
                       feat, W, aff);
    hipLaunchKernelGGL(finalize_kernel, dim3(T_TOK / 256), dim3(256), 0, stream,
                       aff, bias, pref, probs);
    hipLaunchKernelGGL(events_kernel, dim3(1), dim3(512), 0, stream,
                       pref, evt);
    hipLaunchKernelGGL(choice_kernel, dim3(T_TOK / 256), dim3(256), 0, stream,
                       pref, evt, t2e, bcnt);
    hipLaunchKernelGGL(writeout_kernel, dim3(T_TOK / 256), dim3(256), 0, stream,
                       t2e, bcnt, probs, out, out + T_TOK);
}

// Round 4
// 182.488 us; speedup vs baseline: 1.7118x; 1.0173x over previous
//
#include <hip/hip_runtime.h>
#include <hip/hip_bf16.h>
#include <math.h>

#define T_TOK 8192
#define D_MODEL 2048
#define N_EXP 16
#define CAP 512
#define NSEG (T_TOK / 64)           // 128

// ws layout (bytes):
// aff:   0       .. 524288    (unused now; kept for layout stability)
// pref:  524288  .. +65536    u64[T_TOK]
// probs: 589824  .. +524288   float[T_TOK][16]
// evt:   1114112 .. +128      int[32] (evp[16], evf[16])
// gsync: 1114240 .. +8192     int (was t2e, now grid-barrier counter)
// bcnt:  1122432 .. +2048     int[32][16]

__device__ __forceinline__ unsigned int f2ord(float f) {
    unsigned int b = __float_as_uint(f);
    return (b & 0x80000000u) ? ~b : (b | 0x80000000u);
}

// ---------------- Kernel 1: GEMM + fused finalize (softmax + pref build) ----------------
// 1024 blocks x 512 thr (8 waves). Block owns 8 tokens; feat tile (64 KiB) staged to LDS once.
// Wave owns 2 experts; lane slices K. After the butterfly, the 8x16 affinity tile goes to LDS
// and wave w finalizes token w with 16-lane-parallel softmax + rank-based pref build.
// Numerics identical to the old separate finalize: same biased values, fmax is exactly
// associative (same max), sum accumulated in the same e=0..15 order via ordered shfl gather,
// rank-based permutation == selection sort on unique keys.
__global__ __launch_bounds__(512, 4) void gemm_finalize_kernel(
    const float* __restrict__ feat, const float* __restrict__ W,
    const float* __restrict__ bias,
    unsigned long long* __restrict__ pref, float* __restrict__ probs)
{
    __shared__ float flds[8][D_MODEL];   // 64 KiB
    __shared__ float afft[8][N_EXP];     // 512 B

    const int tid  = threadIdx.x;
    const int wave = tid >> 6, lane = tid & 63;
    const int tbase = blockIdx.x * 8;

    {
        const float4* src = (const float4*)(feat + (size_t)tbase * D_MODEL);
        float4* dst = (float4*)&flds[0][0];
        #pragma unroll
        for (int i = 0; i < 8; ++i)
            dst[tid + i * 512] = src[tid + i * 512];
    }

    const float* w0 = W + (size_t)(wave * 2) * D_MODEL + lane * 4;
    const float* w1 = w0 + D_MODEL;

    float acc[16];
    #pragma unroll
    for (int i = 0; i < 16; ++i) acc[i] = 0.f;

    float4 wv0 = *(const float4*)(w0);
    float4 wv1 = *(const float4*)(w1);
    __syncthreads();

    #pragma unroll
    for (int j = 0; j < 8; ++j) {
        float4 wn0, wn1;
        if (j < 7) {
            wn0 = *(const float4*)(w0 + (j + 1) * 256);
            wn1 = *(const float4*)(w1 + (j + 1) * 256);
        } else {
            wn0 = wv0; wn1 = wv1;
        }
        const float* fl = &flds[0][0] + j * 256 + lane * 4;
        #pragma unroll
        for (int r = 0; r < 8; ++r) {
            float4 f = *(const float4*)(fl + r * D_MODEL);
            acc[r * 2 + 0] += f.x * wv0.x;
            acc[r * 2 + 0] += f.y * wv0.y;
            acc[r * 2 + 0] += f.z * wv0.z;
            acc[r * 2 + 0] += f.w * wv0.w;
            acc[r * 2 + 1] += f.x * wv1.x;
            acc[r * 2 + 1] += f.y * wv1.y;
            acc[r * 2 + 1] += f.z * wv1.z;
            acc[r * 2 + 1] += f.w * wv1.w;
        }
        wv0 = wn0; wv1 = wn1;
    }

    #pragma unroll
    for (int step = 0; step < 4; ++step) {
        const int m    = 1 << step;
        const int half = 8 >> step;
        const bool hi  = (lane & m) != 0;
        #pragma unroll
        for (int jj = 0; jj < half; ++jj) {
            float send = hi ? acc[jj] : acc[jj + half];
            float recv = __shfl_xor(send, m, 64);
            acc[jj] = (hi ? acc[jj + half] : acc[jj]) + recv;
        }
    }
    acc[0] += __shfl_xor(acc[0], 16, 64);
    acc[0] += __shfl_xor(acc[0], 32, 64);

    if (lane < 16) {
        const int slot = ((lane & 1) << 3) | (((lane >> 1) & 1) << 2)
                       | (((lane >> 2) & 1) << 1) | ((lane >> 3) & 1);
        const int r = slot >> 1, el = slot & 1;
        afft[r][wave * 2 + el] = acc[0];
    }
    __syncthreads();

    // ---- fused finalize: wave w handles token tbase + w; lane j (mod 16) = expert j ----
    const int tk = tbase + wave;
    const int j  = lane & 15;
    float v = afft[wave][j] + bias[j];       // all 4 16-lane groups hold identical copies

    // max over 16 (fmax tree == chain exactly)
    float mx = v;
    #pragma unroll
    for (int d = 1; d < 16; d <<= 1)
        mx = fmaxf(mx, __shfl_xor(mx, d, 16));

    float ex = __expf(v - mx);

    // ordered sum e=0..15 (identical addend order to the old scalar loop)
    float s = 0.f;
    #pragma unroll
    for (int e2 = 0; e2 < N_EXP; ++e2)
        s += __shfl(ex, e2, 16);

    if (lane < 16)
        probs[(size_t)tk * N_EXP + lane] = ex / s;

    // pref build: rank = #{keys greater}; nibble (15-rank) holds expert j
    unsigned long long key = ((unsigned long long)f2ord(v) << 4)
                           | (unsigned long long)(15 - j);
    int rank = 0;
    #pragma unroll
    for (int d = 1; d < 16; ++d) {
        unsigned long long o = __shfl_xor(key, d, 16);
        rank += (o > key) ? 1 : 0;
    }
    unsigned long long contrib = ((unsigned long long)j) << (4 * (15 - rank));
    #pragma unroll
    for (int d = 1; d < 16; d <<= 1)
        contrib |= __shfl_xor(contrib, d, 16);
    if (lane == 0)
        pref[tk] = contrib;
}

// ---------------- Kernel 2: fill-event schedule, register-resident, 2 barriers/round ----------------
// (verified value-identical in r3; only addition: zero the grid-sync counter for kernel 3)
__global__ __launch_bounds__(512, 1) void events_kernel(
    const unsigned long long* __restrict__ pref, int* __restrict__ evt,
    int* __restrict__ gsync)
{
    __shared__ unsigned long long segmask[N_EXP][NSEG];   // 16 KB
    __shared__ int fparr[N_EXP];

    const int tid  = threadIdx.x;
    const int wave = tid >> 6, lane = tid & 63;
    const unsigned long long lt_mask = (1ull << lane) - 1ull;

    if (tid == 0) *gsync = 0;   // re-arm grid barrier for kernel 3 (stream-ordered)

    unsigned long long myPref[16];
    #pragma unroll
    for (int k = 0; k < 16; ++k) myPref[k] = pref[tid + 512 * k];

    #pragma unroll
    for (int k = 0; k < 16; ++k) {
        const int s = k * 8 + wave;
        const int c = (int)(myPref[k] >> 60);
        #pragma unroll
        for (int e = 0; e < N_EXP; ++e) {
            unsigned long long mm = __ballot(c == e);
            if (lane == e) segmask[e][s] = mm;
        }
    }
    __syncthreads();

    const int eA = wave, eB = wave + 8;
    int capA = CAP, capB = CAP;
    unsigned long long m0A = 0, m1A = 0, m0B = 0, m1B = 0;
    int excl0A = 0, excl1A = 0, excl0B = 0, excl1B = 0;
    int segF = 0;
    unsigned long long mlep = 0;
    unsigned int avail = 0xFFFFu;
    int myp = 0, myf = 0;

    for (int round = 0; round < N_EXP; ++round) {
        {
            int exf = (segF < 64) ? __shfl(excl0A, segF, 64) : __shfl(excl1A, segF - 64, 64);
            unsigned long long mf = (segF < 64) ? __shfl(m0A, segF, 64) : __shfl(m1A, segF - 64, 64);
            capA -= exf + (int)__popcll(mf & mlep);
            exf = (segF < 64) ? __shfl(excl0B, segF, 64) : __shfl(excl1B, segF - 64, 64);
            mf  = (segF < 64) ? __shfl(m0B, segF, 64) : __shfl(m1B, segF - 64, 64);
            capB -= exf + (int)__popcll(mf & mlep);
        }

        unsigned long long a0 = segmask[eA][lane];
        unsigned long long a1 = segmask[eA][64 + lane];
        unsigned long long b0 = segmask[eB][lane];
        unsigned long long b1 = segmask[eB][64 + lane];
        if (lane < segF)            { a0 = 0; b0 = 0; }
        else if (lane == segF)      { a0 &= ~mlep; b0 &= ~mlep; }
        if (64 + lane < segF)       { a1 = 0; b1 = 0; }
        else if (64 + lane == segF) { a1 &= ~mlep; b1 &= ~mlep; }
        m0A = a0; m1A = a1; m0B = b0; m1B = b1;

        const int c0A = (int)__popcll(a0), c1A = (int)__popcll(a1);
        const int c0B = (int)__popcll(b0), c1B = (int)__popcll(b1);
        int v0A = c0A, v1A = c1A, v0B = c0B, v1B = c1B;
        #pragma unroll
        for (int d = 1; d < 64; d <<= 1) {
            int t0 = __shfl_up(v0A, d, 64);
            int t1 = __shfl_up(v1A, d, 64);
            int t2 = __shfl_up(v0B, d, 64);
            int t3 = __shfl_up(v1B, d, 64);
            if (lane >= d) { v0A += t0; v1A += t1; v0B += t2; v1B += t3; }
        }
        const int tot0A = __shfl(v0A, 63, 64);
        const int tot0B = __shfl(v0B, 63, 64);
        excl0A = v0A - c0A;
        excl1A = tot0A + v1A - c1A;
        excl0B = v0B - c0B;
        excl1B = tot0B + v1B - c1B;

        int fpA = 0x7FFFFFFF;
        if ((avail >> eA) & 1u) {
            const int need = capA;
            int segc = -1, kk = 0;
            if (excl0A < need && excl0A + c0A >= need)      { segc = lane;      kk = need - excl0A; }
            else if (excl1A < need && excl1A + c1A >= need) { segc = 64 + lane; kk = need - excl1A; }
            unsigned long long bb = __ballot(segc >= 0);
            if (bb) {
                int l2    = __builtin_ctzll(bb);
                int sstar = __shfl(segc, l2, 64);
                int k2    = __shfl(kk,   l2, 64);
                unsigned long long msel = (sstar < 64) ? __shfl(a0, sstar, 64)
                                                       : __shfl(a1, sstar - 64, 64);
                int rr = (int)__popcll(msel & lt_mask);
                bool hit = ((msel >> lane) & 1ull) && (rr == k2 - 1);
                unsigned long long hb = __ballot(hit);
                fpA = sstar * 64 + __builtin_ctzll(hb);
            }
        }
        int fpB = 0x7FFFFFFF;
        if ((avail >> eB) & 1u) {
            const int need = capB;
            int segc = -1, kk = 0;
            if (excl0B < need && excl0B + c0B >= need)      { segc = lane;      kk = need - excl0B; }
            else if (excl1B < need && excl1B + c1B >= need) { segc = 64 + lane; kk = need - excl1B; }
            unsigned long long bb = __ballot(segc >= 0);
            if (bb) {
                int l2    = __builtin_ctzll(bb);
                int sstar = __shfl(segc, l2, 64);
                int k2    = __shfl(kk,   l2, 64);
                unsigned long long msel = (sstar < 64) ? __shfl(b0, sstar, 64)
                                                       : __shfl(b1, sstar - 64, 64);
                int rr = (int)__popcll(msel & lt_mask);
                bool hit = ((msel >> lane) & 1ull) && (rr == k2 - 1);
                unsigned long long hb = __ballot(hit);
                fpB = sstar * 64 + __builtin_ctzll(hb);
            }
        }
        if (lane == 0) { fparr[eA] = fpA; fparr[eB] = fpB; }
        __syncthreads();

        int pmin = 0x7FFFFFFF, fe = 0;
        #pragma unroll
        for (int e = 0; e < N_EXP; ++e) {
            int f = fparr[e];
            if (f < pmin) { pmin = f; fe = e; }
        }
        if (tid == round) { myp = pmin; myf = fe; }

        const int nsegF = pmin >> 6;
        const unsigned long long nmlep = ((pmin & 63) == 63) ? ~0ull
                                         : ((1ull << ((pmin & 63) + 1)) - 1ull);
        const unsigned int navail = avail & ~(1u << fe);

        if (round < N_EXP - 1) {
            #pragma unroll
            for (int k = 0; k < 16; ++k) {
                const int s = k * 8 + wave;
                if (s >= nsegF) {
                    unsigned long long m = segmask[fe][s];
                    if (s == nsegF) m &= ~nmlep;
                    if ((m >> lane) & 1ull) {
                        unsigned long long pp = myPref[k];
                        int e2 = (int)(pp >> 60);
                        while (!((navail >> e2) & 1u)) { pp <<= 4; e2 = (int)(pp >> 60); }
                        atomicOr(&segmask[e2][s], 1ull << lane);
                    }
                }
            }
        }
        segF = nsegF; mlep = nmlep; avail = navail;
        __syncthreads();
    }

    if (tid < N_EXP) { evt[tid] = myp; evt[N_EXP + tid] = myf; }
}

// ---------------- Kernel 3: fused choice + writeout (manual grid barrier, 32 co-resident blocks) ----------------
// Phase 1 == old choice_kernel (same e walk, same ballots); bcnt published via device-scope
// atomicExch. Grid barrier: arrive on gsync (zeroed by events), spin to 32 — 32 blocks of 256
// threads are always co-resident on 256 CUs, so no deadlock. Phase 2 == old writeout_kernel,
// reusing phase-1's in-register own/sc (identical values).
__global__ __launch_bounds__(256) void choice_write_kernel(
    const unsigned long long* __restrict__ pref, const int* __restrict__ evt,
    const float* __restrict__ probs, int* __restrict__ bcnt, int* __restrict__ gsync,
    float* __restrict__ out0, float* __restrict__ out1)
{
    __shared__ int evp[N_EXP], evf[N_EXP];
    __shared__ int sc[4][N_EXP];
    __shared__ int base[N_EXP];
    const int tid = threadIdx.x, b = blockIdx.x;
    const int wave = tid >> 6, lane = tid & 63;
    const unsigned long long lt_mask = (1ull << lane) - 1ull;

    if (tid < N_EXP) evp[tid] = evt[tid];
    else if (tid < 2 * N_EXP) evf[tid - N_EXP] = evt[tid];
    __syncthreads();

    const int t = b * 256 + tid;
    unsigned int mask = 0xFFFFu;
    #pragma unroll
    for (int jj = 0; jj < N_EXP; ++jj)
        if (evp[jj] < t) mask &= ~(1u << evf[jj]);

    unsigned long long pp = pref[t];
    int e = (int)(pp >> 60);
    while (!((mask >> e) & 1u)) { pp <<= 4; e = (int)(pp >> 60); }

    unsigned long long own = 0ull;
    #pragma unroll
    for (int e2 = 0; e2 < N_EXP; ++e2) {
        unsigned long long mm = __ballot(e == e2);
        if (e == e2) own = mm;
        if (lane == e2) sc[wave][e2] = (int)__popcll(mm);
    }
    __syncthreads();

    // publish per-block counts (device-scope atomics: coherent across XCD L2s)
    if (tid < N_EXP)
        atomicExch(&bcnt[b * N_EXP + tid],
                   sc[0][tid] + sc[1][tid] + sc[2][tid] + sc[3][tid]);
    __syncthreads();

    // grid barrier
    if (tid == 0) {
        __threadfence();
        atomicAdd(gsync, 1);
        while (atomicAdd(gsync, 0) < 32) { __builtin_amdgcn_s_sleep(2); }
    }
    __syncthreads();

    // phase 2: base = per-expert count over preceding blocks (atomic reads, coherent)
    if (tid < N_EXP) {
        int s = 0;
        for (int b2 = 0; b2 < b; ++b2) s += atomicAdd(&bcnt[b2 * N_EXP + tid], 0);
        base[tid] = s;
    }
    __syncthreads();

    int rank = (int)__popcll(own & lt_mask);
    for (int w2 = 0; w2 < wave; ++w2) rank += sc[w2][e];
    const int pos = base[e] + rank;
    out0[e * CAP + pos] = (float)t;
    out1[t] = probs[(size_t)t * N_EXP + e];
}

extern "C" void kernel_launch(void* const* d_in, const int* in_sizes, int n_in,
                              void* d_out, int out_size, void* d_ws, size_t ws_size,
                              hipStream_t stream) {
    const float* feat = (const float*)d_in[0];
    const float* W    = (const float*)d_in[1];
    const float* bias = (const float*)d_in[2];

    float* out = (float*)d_out;
    char*  ws  = (char*)d_ws;

    unsigned long long* pref = (unsigned long long*)(ws + 524288);
    float* probs             = (float*)(ws + 589824);
    int* evt                 = (int*)(ws + 1114112);
    int* gsync               = (int*)(ws + 1114240);
    int* bcnt                = (int*)(ws + 1122432);

    hipLaunchKernelGGL(gemm_finalize_kernel, dim3(T_TOK / 8), dim3(512), 0, stream,
                       feat, W, bias, pref, probs);
    hipLaunchKernelGGL(events_kernel, dim3(1), dim3(512), 0, stream,
                       pref, evt, gsync);
    hipLaunchKernelGGL(choice_write_kernel, dim3(T_TOK / 256), dim3(256), 0, stream,
                       pref, evt, probs, bcnt, gsync, out, out + T_TOK);
}

// Round 5
// 175.436 us; speedup vs baseline: 1.7806x; 1.0402x over previous
//
#include <hip/hip_runtime.h>
#include <hip/hip_bf16.h>
#include <math.h>

#define T_TOK 8192
#define D_MODEL 2048
#define N_EXP 16
#define CAP 512
#define NSEG (T_TOK / 64)           // 128

// ws layout (bytes):
// aff:   0       .. 524288    (unused; layout stability)
// pref:  524288  .. +65536    u64[T_TOK]
// probs: 589824  .. +524288   float[T_TOK][16]
// evt:   1114112 .. +128      int[32] (evp[16], evf[16])
// gsync: 1114240 .. +8192     int[2] grid-barrier counters (armed by K1 each iteration)
// bcnt:  1122432 .. +2048     int[16][16]

__device__ __forceinline__ unsigned int f2ord(float f) {
    unsigned int b = __float_as_uint(f);
    return (b & 0x80000000u) ? ~b : (b | 0x80000000u);
}

// direct global->LDS DMA, 16 B per lane, no VGPR round-trip
#define GLOBAL_LOAD_LDS16(g, l)                                            \
    __builtin_amdgcn_global_load_lds(                                      \
        (const __attribute__((address_space(1))) unsigned int*)(g),        \
        (__attribute__((address_space(3))) unsigned int*)(l), 16, 0, 0)

// ---------------- Kernel 1: GEMM + fused finalize (softmax + pref build) ----------------
// 1024 blocks x 512 thr (8 waves). Block owns 8 tokens; feat tile (64 KiB) staged to LDS via
// global_load_lds (wave-uniform base + lane*16 layout matches flds linear layout exactly) --
// zero staging VGPRs/VALU. No launch_bounds occupancy cap: let the allocator keep acc[16]
// resident (r0/r1/r4 all spilled at the 64-VGPR target; WRITE_SIZE is the tripwire).
// Math identical to verified r4: same K slices, FMA order, butterfly merge order, finalize.
__global__ __launch_bounds__(512) void gemm_finalize_kernel(
    const float* __restrict__ feat, const float* __restrict__ W,
    const float* __restrict__ bias,
    unsigned long long* __restrict__ pref, float* __restrict__ probs,
    int* __restrict__ gsync)
{
    __shared__ float flds[8][D_MODEL];   // 64 KiB
    __shared__ float afft[8][N_EXP];     // 512 B

    const int tid  = threadIdx.x;
    const int wave = tid >> 6, lane = tid & 63;
    const int tbase = blockIdx.x * 8;

    // arm the grid-barrier counters for kernel 2 (stream-ordered; robust to ws poisoning)
    if (blockIdx.x == 0 && tid == 0) { gsync[0] = 0; gsync[1] = 0; }

    // stage feat tile: 4096 x 16 B, direct to LDS (per (wave,i): base uniform, +lane*16)
    {
        const float* src = feat + (size_t)tbase * D_MODEL;
        #pragma unroll
        for (int i = 0; i < 8; ++i) {
            const int idx = tid + i * 512;           // float4 index
            GLOBAL_LOAD_LDS16(src + (size_t)idx * 4, &flds[0][0] + (size_t)idx * 4);
        }
    }

    const float* w0 = W + (size_t)(wave * 2) * D_MODEL + lane * 4;
    const float* w1 = w0 + D_MODEL;

    float acc[16];
    #pragma unroll
    for (int i = 0; i < 16; ++i) acc[i] = 0.f;

    float4 wv0 = *(const float4*)(w0);
    float4 wv1 = *(const float4*)(w1);
    __syncthreads();   // drains the global_load_lds queue (vmcnt) + W prefetch

    #pragma unroll
    for (int j = 0; j < 8; ++j) {
        float4 wn0, wn1;
        if (j < 7) {
            wn0 = *(const float4*)(w0 + (j + 1) * 256);
            wn1 = *(const float4*)(w1 + (j + 1) * 256);
        } else {
            wn0 = wv0; wn1 = wv1;
        }
        const float* fl = &flds[0][0] + j * 256 + lane * 4;
        #pragma unroll
        for (int r = 0; r < 8; ++r) {
            float4 f = *(const float4*)(fl + r * D_MODEL);
            acc[r * 2 + 0] += f.x * wv0.x;
            acc[r * 2 + 0] += f.y * wv0.y;
            acc[r * 2 + 0] += f.z * wv0.z;
            acc[r * 2 + 0] += f.w * wv0.w;
            acc[r * 2 + 1] += f.x * wv1.x;
            acc[r * 2 + 1] += f.y * wv1.y;
            acc[r * 2 + 1] += f.z * wv1.z;
            acc[r * 2 + 1] += f.w * wv1.w;
        }
        wv0 = wn0; wv1 = wn1;
    }

    #pragma unroll
    for (int step = 0; step < 4; ++step) {
        const int m    = 1 << step;
        const int half = 8 >> step;
        const bool hi  = (lane & m) != 0;
        #pragma unroll
        for (int jj = 0; jj < half; ++jj) {
            float send = hi ? acc[jj] : acc[jj + half];
            float recv = __shfl_xor(send, m, 64);
            acc[jj] = (hi ? acc[jj + half] : acc[jj]) + recv;
        }
    }
    acc[0] += __shfl_xor(acc[0], 16, 64);
    acc[0] += __shfl_xor(acc[0], 32, 64);

    if (lane < 16) {
        const int slot = ((lane & 1) << 3) | (((lane >> 1) & 1) << 2)
                       | (((lane >> 2) & 1) << 1) | ((lane >> 3) & 1);
        const int r = slot >> 1, el = slot & 1;
        afft[r][wave * 2 + el] = acc[0];
    }
    __syncthreads();

    // ---- fused finalize: wave w handles token tbase + w; lane j (mod 16) = expert j ----
    const int tk = tbase + wave;
    const int j  = lane & 15;
    float v = afft[wave][j] + bias[j];

    float mx = v;
    #pragma unroll
    for (int d = 1; d < 16; d <<= 1)
        mx = fmaxf(mx, __shfl_xor(mx, d, 16));

    float ex = __expf(v - mx);

    float s = 0.f;
    #pragma unroll
    for (int e2 = 0; e2 < N_EXP; ++e2)
        s += __shfl(ex, e2, 16);

    if (lane < 16)
        probs[(size_t)tk * N_EXP + lane] = ex / s;

    unsigned long long key = ((unsigned long long)f2ord(v) << 4)
                           | (unsigned long long)(15 - j);
    int rank = 0;
    #pragma unroll
    for (int d = 1; d < 16; ++d) {
        unsigned long long o = __shfl_xor(key, d, 16);
        rank += (o > key) ? 1 : 0;
    }
    unsigned long long contrib = ((unsigned long long)j) << (4 * (15 - rank));
    #pragma unroll
    for (int d = 1; d < 16; d <<= 1)
        contrib |= __shfl_xor(contrib, d, 16);
    if (lane == 0)
        pref[tk] = contrib;
}

// ---------------- Kernel 2: events (block 0) + grid barrier + choice + writeout ----------------
// 16 blocks x 512 thr (trivially co-resident on 256 CUs). Block 0 runs the verified r3 events
// body; evt published via device-scope atomics. Barrier counters armed by K1 (stream-ordered),
// so the scheme is robust to workspace poisoning. Then each block handles 512 tokens with the
// verified choice/write math (8-wave sc instead of 4-wave; pos is the same pure function of
// token order, so outputs are value-identical).
__global__ __launch_bounds__(512, 1) void events_choice_write_kernel(
    const unsigned long long* __restrict__ pref, const float* __restrict__ probs,
    int* __restrict__ evt, int* __restrict__ gsync, int* __restrict__ bcnt,
    float* __restrict__ out0, float* __restrict__ out1)
{
    __shared__ unsigned long long segmask[N_EXP][NSEG];   // 16 KB
    __shared__ int fparr[N_EXP];
    __shared__ int evp[N_EXP], evf[N_EXP];
    __shared__ int sc[8][N_EXP];
    __shared__ int base[N_EXP];

    const int tid  = threadIdx.x;
    const int wave = tid >> 6, lane = tid & 63;
    const unsigned long long lt_mask = (1ull << lane) - 1ull;
    const int b = blockIdx.x;

    if (b == 0) {
        // ================= events body (verified r3, verbatim) =================
        unsigned long long myPref[16];
        #pragma unroll
        for (int k = 0; k < 16; ++k) myPref[k] = pref[tid + 512 * k];

        #pragma unroll
        for (int k = 0; k < 16; ++k) {
            const int s = k * 8 + wave;
            const int c = (int)(myPref[k] >> 60);
            #pragma unroll
            for (int e = 0; e < N_EXP; ++e) {
                unsigned long long mm = __ballot(c == e);
                if (lane == e) segmask[e][s] = mm;
            }
        }
        __syncthreads();

        const int eA = wave, eB = wave + 8;
        int capA = CAP, capB = CAP;
        unsigned long long m0A = 0, m1A = 0, m0B = 0, m1B = 0;
        int excl0A = 0, excl1A = 0, excl0B = 0, excl1B = 0;
        int segF = 0;
        unsigned long long mlep = 0;
        unsigned int avail = 0xFFFFu;
        int myp = 0, myf = 0;

        for (int round = 0; round < N_EXP; ++round) {
            {
                int exf = (segF < 64) ? __shfl(excl0A, segF, 64) : __shfl(excl1A, segF - 64, 64);
                unsigned long long mf = (segF < 64) ? __shfl(m0A, segF, 64) : __shfl(m1A, segF - 64, 64);
                capA -= exf + (int)__popcll(mf & mlep);
                exf = (segF < 64) ? __shfl(excl0B, segF, 64) : __shfl(excl1B, segF - 64, 64);
                mf  = (segF < 64) ? __shfl(m0B, segF, 64) : __shfl(m1B, segF - 64, 64);
                capB -= exf + (int)__popcll(mf & mlep);
            }

            unsigned long long a0 = segmask[eA][lane];
            unsigned long long a1 = segmask[eA][64 + lane];
            unsigned long long b0 = segmask[eB][lane];
            unsigned long long b1 = segmask[eB][64 + lane];
            if (lane < segF)            { a0 = 0; b0 = 0; }
            else if (lane == segF)      { a0 &= ~mlep; b0 &= ~mlep; }
            if (64 + lane < segF)       { a1 = 0; b1 = 0; }
            else if (64 + lane == segF) { a1 &= ~mlep; b1 &= ~mlep; }
            m0A = a0; m1A = a1; m0B = b0; m1B = b1;

            const int c0A = (int)__popcll(a0), c1A = (int)__popcll(a1);
            const int c0B = (int)__popcll(b0), c1B = (int)__popcll(b1);
            int v0A = c0A, v1A = c1A, v0B = c0B, v1B = c1B;
            #pragma unroll
            for (int d = 1; d < 64; d <<= 1) {
                int t0 = __shfl_up(v0A, d, 64);
                int t1 = __shfl_up(v1A, d, 64);
                int t2 = __shfl_up(v0B, d, 64);
                int t3 = __shfl_up(v1B, d, 64);
                if (lane >= d) { v0A += t0; v1A += t1; v0B += t2; v1B += t3; }
            }
            const int tot0A = __shfl(v0A, 63, 64);
            const int tot0B = __shfl(v0B, 63, 64);
            excl0A = v0A - c0A;
            excl1A = tot0A + v1A - c1A;
            excl0B = v0B - c0B;
            excl1B = tot0B + v1B - c1B;

            int fpA = 0x7FFFFFFF;
            if ((avail >> eA) & 1u) {
                const int need = capA;
                int segc = -1, kk = 0;
                if (excl0A < need && excl0A + c0A >= need)      { segc = lane;      kk = need - excl0A; }
                else if (excl1A < need && excl1A + c1A >= need) { segc = 64 + lane; kk = need - excl1A; }
                unsigned long long bb = __ballot(segc >= 0);
                if (bb) {
                    int l2    = __builtin_ctzll(bb);
                    int sstar = __shfl(segc, l2, 64);
                    int k2    = __shfl(kk,   l2, 64);
                    unsigned long long msel = (sstar < 64) ? __shfl(a0, sstar, 64)
                                                           : __shfl(a1, sstar - 64, 64);
                    int rr = (int)__popcll(msel & lt_mask);
                    bool hit = ((msel >> lane) & 1ull) && (rr == k2 - 1);
                    unsigned long long hb = __ballot(hit);
                    fpA = sstar * 64 + __builtin_ctzll(hb);
                }
            }
            int fpB = 0x7FFFFFFF;
            if ((avail >> eB) & 1u) {
                const int need = capB;
                int segc = -1, kk = 0;
                if (excl0B < need && excl0B + c0B >= need)      { segc = lane;      kk = need - excl0B; }
                else if (excl1B < need && excl1B + c1B >= need) { segc = 64 + lane; kk = need - excl1B; }
                unsigned long long bb = __ballot(segc >= 0);
                if (bb) {
                    int l2    = __builtin_ctzll(bb);
                    int sstar = __shfl(segc, l2, 64);
                    int k2    = __shfl(kk,   l2, 64);
                    unsigned long long msel = (sstar < 64) ? __shfl(b0, sstar, 64)
                                                           : __shfl(b1, sstar - 64, 64);
                    int rr = (int)__popcll(msel & lt_mask);
                    bool hit = ((msel >> lane) & 1ull) && (rr == k2 - 1);
                    unsigned long long hb = __ballot(hit);
                    fpB = sstar * 64 + __builtin_ctzll(hb);
                }
            }
            if (lane == 0) { fparr[eA] = fpA; fparr[eB] = fpB; }
            __syncthreads();

            int pmin = 0x7FFFFFFF, fe = 0;
            #pragma unroll
            for (int e = 0; e < N_EXP; ++e) {
                int f = fparr[e];
                if (f < pmin) { pmin = f; fe = e; }
            }
            if (tid == round) { myp = pmin; myf = fe; }

            const int nsegF = pmin >> 6;
            const unsigned long long nmlep = ((pmin & 63) == 63) ? ~0ull
                                             : ((1ull << ((pmin & 63) + 1)) - 1ull);
            const unsigned int navail = avail & ~(1u << fe);

            if (round < N_EXP - 1) {
                #pragma unroll
                for (int k = 0; k < 16; ++k) {
                    const int s = k * 8 + wave;
                    if (s >= nsegF) {
                        unsigned long long m = segmask[fe][s];
                        if (s == nsegF) m &= ~nmlep;
                        if ((m >> lane) & 1ull) {
                            unsigned long long pp = myPref[k];
                            int e2 = (int)(pp >> 60);
                            while (!((navail >> e2) & 1u)) { pp <<= 4; e2 = (int)(pp >> 60); }
                            atomicOr(&segmask[e2][s], 1ull << lane);
                        }
                    }
                }
            }
            segF = nsegF; mlep = nmlep; avail = navail;
            __syncthreads();
        }

        if (tid < N_EXP) {
            atomicExch(&evt[tid], myp);
            atomicExch(&evt[N_EXP + tid], myf);
        }
        // ================= end events body =================
    }

    // ---- grid barrier 1 (16 blocks; counter armed to 0 by K1) ----
    __syncthreads();
    if (tid == 0) {
        __threadfence();
        atomicAdd(&gsync[0], 1);
        while (atomicAdd(&gsync[0], 0) < 16) { __builtin_amdgcn_s_sleep(2); }
        __threadfence();
    }
    __syncthreads();

    // ---- choice phase: token t = b*512 + tid ----
    if (tid < N_EXP) evp[tid] = atomicAdd(&evt[tid], 0);
    else if (tid < 2 * N_EXP) evf[tid - N_EXP] = atomicAdd(&evt[tid], 0);
    __syncthreads();

    const int t = b * 512 + tid;
    unsigned int mask = 0xFFFFu;
    #pragma unroll
    for (int jj = 0; jj < N_EXP; ++jj)
        if (evp[jj] < t) mask &= ~(1u << evf[jj]);

    unsigned long long pp = pref[t];
    int e = (int)(pp >> 60);
    while (!((mask >> e) & 1u)) { pp <<= 4; e = (int)(pp >> 60); }

    unsigned long long own = 0ull;
    #pragma unroll
    for (int e2 = 0; e2 < N_EXP; ++e2) {
        unsigned long long mm = __ballot(e == e2);
        if (e == e2) own = mm;
        if (lane == e2) sc[wave][e2] = (int)__popcll(mm);
    }
    __syncthreads();

    if (tid < N_EXP) {
        int s = 0;
        #pragma unroll
        for (int w2 = 0; w2 < 8; ++w2) s += sc[w2][tid];
        atomicExch(&bcnt[b * N_EXP + tid], s);
    }

    // ---- grid barrier 2 ----
    __syncthreads();
    if (tid == 0) {
        __threadfence();
        atomicAdd(&gsync[1], 1);
        while (atomicAdd(&gsync[1], 0) < 16) { __builtin_amdgcn_s_sleep(2); }
        __threadfence();
    }
    __syncthreads();

    // ---- writeout phase ----
    if (tid < N_EXP) {
        int s = 0;
        for (int b2 = 0; b2 < b; ++b2) s += atomicAdd(&bcnt[b2 * N_EXP + tid], 0);
        base[tid] = s;
    }
    __syncthreads();

    int rank = (int)__popcll(own & lt_mask);
    for (int w2 = 0; w2 < wave; ++w2) rank += sc[w2][e];
    const int pos = base[e] + rank;
    out0[e * CAP + pos] = (float)t;
    out1[t] = probs[(size_t)t * N_EXP + e];
}

extern "C" void kernel_launch(void* const* d_in, const int* in_sizes, int n_in,
                              void* d_out, int out_size, void* d_ws, size_t ws_size,
                              hipStream_t stream) {
    const float* feat = (const float*)d_in[0];
    const float* W    = (const float*)d_in[1];
    const float* bias = (const float*)d_in[2];

    float* out = (float*)d_out;
    char*  ws  = (char*)d_ws;

    unsigned long long* pref = (unsigned long long*)(ws + 524288);
    float* probs             = (float*)(ws + 589824);
    int* evt                 = (int*)(ws + 1114112);
    int* gsync               = (int*)(ws + 1114240);
    int* bcnt                = (int*)(ws + 1122432);

    hipLaunchKernelGGL(gemm_finalize_kernel, dim3(T_TOK / 8), dim3(512), 0, stream,
                       feat, W, bias, pref, probs, gsync);
    hipLaunchKernelGGL(events_choice_write_kernel, dim3(16), dim3(512), 0, stream,
                       pref, probs, evt, gsync, bcnt, out, out + T_TOK);
}

// Round 6
// 169.190 us; speedup vs baseline: 1.8463x; 1.0369x over previous
//
#include <hip/hip_runtime.h>
#include <hip/hip_bf16.h>
#include <math.h>

#define T_TOK 8192
#define D_MODEL 2048
#define N_EXP 16
#define CAP 512
#define NSEG (T_TOK / 64)           // 128

// ws layout (bytes):
// aff:   0       .. 524288    (unused; layout stability)
// pref:  524288  .. +65536    u64[T_TOK]
// probs: 589824  .. +524288   float[T_TOK][16]
// evt:   1114112 .. +128      int[32] (evp[16], evf[16])
// gsync: 1114240 .. +8192     int[2] grid-barrier counters (armed by K1 each iteration)
// bcnt:  1122432 .. +2048     int[16][16]

__device__ __forceinline__ unsigned int f2ord(float f) {
    unsigned int b = __float_as_uint(f);
    return (b & 0x80000000u) ? ~b : (b | 0x80000000u);
}

// direct global->LDS DMA, 16 B per lane, no VGPR round-trip
#define GLOBAL_LOAD_LDS16(g, l)                                            \
    __builtin_amdgcn_global_load_lds(                                      \
        (const __attribute__((address_space(1))) unsigned int*)(g),        \
        (__attribute__((address_space(3))) unsigned int*)(l), 16, 0, 0)

// read a u64 register from a (uniform) lane as a scalar — no ds_bpermute
__device__ __forceinline__ unsigned long long rdlane64(unsigned long long v, int l) {
    unsigned int lo = (unsigned int)__builtin_amdgcn_readlane((int)(unsigned int)(v & 0xFFFFFFFFull), l);
    unsigned int hi = (unsigned int)__builtin_amdgcn_readlane((int)(unsigned int)(v >> 32), l);
    return ((unsigned long long)hi << 32) | (unsigned long long)lo;
}

// wave64 inclusive int scan: 4 DPP row_shr adds (intra-row16) + readlane fixups.
// Integer adds -> result identical to the shfl_up ladder it replaces.
__device__ __forceinline__ int wave_incl_scan(int x, int lane) {
    x += __builtin_amdgcn_update_dpp(0, x, 0x111, 0xF, 0xF, false);  // row_shr:1
    x += __builtin_amdgcn_update_dpp(0, x, 0x112, 0xF, 0xF, false);  // row_shr:2
    x += __builtin_amdgcn_update_dpp(0, x, 0x114, 0xF, 0xF, false);  // row_shr:4
    x += __builtin_amdgcn_update_dpp(0, x, 0x118, 0xF, 0xF, false);  // row_shr:8
    const int r15 = __builtin_amdgcn_readlane(x, 15);   // row0 total
    const int r47 = __builtin_amdgcn_readlane(x, 47);   // row2 total
    const int grp = lane & 48;
    if (grp == 16) x += r15;          // row1 += row0
    else if (grp == 48) x += r47;     // row3 += row2
    const int r31 = __builtin_amdgcn_readlane(x, 31);   // rows0+1 total
    if (lane >= 32) x += r31;         // upper half += lower-half total
    return x;
}

// ---------------- Kernel 1: GEMM + fused finalize (verified r5, verbatim) ----------------
__global__ __launch_bounds__(512) void gemm_finalize_kernel(
    const float* __restrict__ feat, const float* __restrict__ W,
    const float* __restrict__ bias,
    unsigned long long* __restrict__ pref, float* __restrict__ probs,
    int* __restrict__ gsync)
{
    __shared__ float flds[8][D_MODEL];   // 64 KiB
    __shared__ float afft[8][N_EXP];     // 512 B

    const int tid  = threadIdx.x;
    const int wave = tid >> 6, lane = tid & 63;
    const int tbase = blockIdx.x * 8;

    if (blockIdx.x == 0 && tid == 0) { gsync[0] = 0; gsync[1] = 0; }

    {
        const float* src = feat + (size_t)tbase * D_MODEL;
        #pragma unroll
        for (int i = 0; i < 8; ++i) {
            const int idx = tid + i * 512;           // float4 index
            GLOBAL_LOAD_LDS16(src + (size_t)idx * 4, &flds[0][0] + (size_t)idx * 4);
        }
    }

    const float* w0 = W + (size_t)(wave * 2) * D_MODEL + lane * 4;
    const float* w1 = w0 + D_MODEL;

    float acc[16];
    #pragma unroll
    for (int i = 0; i < 16; ++i) acc[i] = 0.f;

    float4 wv0 = *(const float4*)(w0);
    float4 wv1 = *(const float4*)(w1);
    __syncthreads();

    #pragma unroll
    for (int j = 0; j < 8; ++j) {
        float4 wn0, wn1;
        if (j < 7) {
            wn0 = *(const float4*)(w0 + (j + 1) * 256);
            wn1 = *(const float4*)(w1 + (j + 1) * 256);
        } else {
            wn0 = wv0; wn1 = wv1;
        }
        const float* fl = &flds[0][0] + j * 256 + lane * 4;
        #pragma unroll
        for (int r = 0; r < 8; ++r) {
            float4 f = *(const float4*)(fl + r * D_MODEL);
            acc[r * 2 + 0] += f.x * wv0.x;
            acc[r * 2 + 0] += f.y * wv0.y;
            acc[r * 2 + 0] += f.z * wv0.z;
            acc[r * 2 + 0] += f.w * wv0.w;
            acc[r * 2 + 1] += f.x * wv1.x;
            acc[r * 2 + 1] += f.y * wv1.y;
            acc[r * 2 + 1] += f.z * wv1.z;
            acc[r * 2 + 1] += f.w * wv1.w;
        }
        wv0 = wn0; wv1 = wn1;
    }

    #pragma unroll
    for (int step = 0; step < 4; ++step) {
        const int m    = 1 << step;
        const int half = 8 >> step;
        const bool hi  = (lane & m) != 0;
        #pragma unroll
        for (int jj = 0; jj < half; ++jj) {
            float send = hi ? acc[jj] : acc[jj + half];
            float recv = __shfl_xor(send, m, 64);
            acc[jj] = (hi ? acc[jj + half] : acc[jj]) + recv;
        }
    }
    acc[0] += __shfl_xor(acc[0], 16, 64);
    acc[0] += __shfl_xor(acc[0], 32, 64);

    if (lane < 16) {
        const int slot = ((lane & 1) << 3) | (((lane >> 1) & 1) << 2)
                       | (((lane >> 2) & 1) << 1) | ((lane >> 3) & 1);
        const int r = slot >> 1, el = slot & 1;
        afft[r][wave * 2 + el] = acc[0];
    }
    __syncthreads();

    const int tk = tbase + wave;
    const int j  = lane & 15;
    float v = afft[wave][j] + bias[j];

    float mx = v;
    #pragma unroll
    for (int d = 1; d < 16; d <<= 1)
        mx = fmaxf(mx, __shfl_xor(mx, d, 16));

    float ex = __expf(v - mx);

    float s = 0.f;
    #pragma unroll
    for (int e2 = 0; e2 < N_EXP; ++e2)
        s += __shfl(ex, e2, 16);

    if (lane < 16)
        probs[(size_t)tk * N_EXP + lane] = ex / s;

    unsigned long long key = ((unsigned long long)f2ord(v) << 4)
                           | (unsigned long long)(15 - j);
    int rank = 0;
    #pragma unroll
    for (int d = 1; d < 16; ++d) {
        unsigned long long o = __shfl_xor(key, d, 16);
        rank += (o > key) ? 1 : 0;
    }
    unsigned long long contrib = ((unsigned long long)j) << (4 * (15 - rank));
    #pragma unroll
    for (int d = 1; d < 16; d <<= 1)
        contrib |= __shfl_xor(contrib, d, 16);
    if (lane == 0)
        pref[tk] = contrib;
}

// ---------------- Kernel 2: events (block 0, DPP/readlane round body) + choice + writeout ----------------
// Same algorithm/values as verified r5; only cross-lane PRIMITIVES changed:
// scan = DPP row_shr + readlane fixups (integer-exact), uniform-index shuffles = readlane,
// writeout base-sum = parallel gather. Barrier counters armed by K1 (stream-ordered).
__global__ __launch_bounds__(512, 1) void events_choice_write_kernel(
    const unsigned long long* __restrict__ pref, const float* __restrict__ probs,
    int* __restrict__ evt, int* __restrict__ gsync, int* __restrict__ bcnt,
    float* __restrict__ out0, float* __restrict__ out1)
{
    __shared__ unsigned long long segmask[N_EXP][NSEG];   // 16 KB
    __shared__ int fparr[N_EXP];
    __shared__ int evp[N_EXP], evf[N_EXP];
    __shared__ int sc[8][N_EXP];
    __shared__ int base[N_EXP];
    __shared__ int pcnt[16][N_EXP];

    const int tid  = threadIdx.x;
    const int wave = tid >> 6, lane = tid & 63;
    const unsigned long long lt_mask = (1ull << lane) - 1ull;
    const int b = blockIdx.x;

    if (b == 0) {
        // ================= events body =================
        unsigned long long myPref[16];
        #pragma unroll
        for (int k = 0; k < 16; ++k) myPref[k] = pref[tid + 512 * k];

        #pragma unroll
        for (int k = 0; k < 16; ++k) {
            const int s = k * 8 + wave;
            const int c = (int)(myPref[k] >> 60);
            #pragma unroll
            for (int e = 0; e < N_EXP; ++e) {
                unsigned long long mm = __ballot(c == e);
                if (lane == e) segmask[e][s] = mm;
            }
        }
        __syncthreads();

        const int eA = wave, eB = wave + 8;
        int capA = CAP, capB = CAP;
        unsigned long long m0A = 0, m1A = 0, m0B = 0, m1B = 0;
        int excl0A = 0, excl1A = 0, excl0B = 0, excl1B = 0;
        int segF = 0;
        unsigned long long mlep = 0;
        unsigned int avail = 0xFFFFu;
        int myp = 0, myf = 0;

        for (int round = 0; round < N_EXP; ++round) {
            // ---- capacity commit from previous round (scalar readlane; no-op at round 0) ----
            {
                const int sFs = __builtin_amdgcn_readfirstlane(segF);
                int exfA, exfB;
                unsigned long long mfA, mfB;
                if (sFs < 64) {
                    exfA = __builtin_amdgcn_readlane(excl0A, sFs);
                    exfB = __builtin_amdgcn_readlane(excl0B, sFs);
                    mfA  = rdlane64(m0A, sFs);
                    mfB  = rdlane64(m0B, sFs);
                } else {
                    exfA = __builtin_amdgcn_readlane(excl1A, sFs - 64);
                    exfB = __builtin_amdgcn_readlane(excl1B, sFs - 64);
                    mfA  = rdlane64(m1A, sFs - 64);
                    mfB  = rdlane64(m1B, sFs - 64);
                }
                capA -= exfA + (int)__popcll(mfA & mlep);
                capB -= exfB + (int)__popcll(mfB & mlep);
            }

            // ---- load masks + lazy in-register prune ----
            unsigned long long a0 = segmask[eA][lane];
            unsigned long long a1 = segmask[eA][64 + lane];
            unsigned long long b0 = segmask[eB][lane];
            unsigned long long b1 = segmask[eB][64 + lane];
            if (lane < segF)            { a0 = 0; b0 = 0; }
            else if (lane == segF)      { a0 &= ~mlep; b0 &= ~mlep; }
            if (64 + lane < segF)       { a1 = 0; b1 = 0; }
            else if (64 + lane == segF) { a1 &= ~mlep; b1 &= ~mlep; }
            m0A = a0; m1A = a1; m0B = b0; m1B = b1;

            // ---- 4 inclusive scans via DPP (integer-exact) ----
            const int c0A = (int)__popcll(a0), c1A = (int)__popcll(a1);
            const int c0B = (int)__popcll(b0), c1B = (int)__popcll(b1);
            const int v0A = wave_incl_scan(c0A, lane);
            const int v1A = wave_incl_scan(c1A, lane);
            const int v0B = wave_incl_scan(c0B, lane);
            const int v1B = wave_incl_scan(c1B, lane);
            const int tot0A = __builtin_amdgcn_readlane(v0A, 63);
            const int tot0B = __builtin_amdgcn_readlane(v0B, 63);
            excl0A = v0A - c0A;
            excl1A = tot0A + v1A - c1A;
            excl0B = v0B - c0B;
            excl1B = tot0B + v1B - c1B;

            // ---- crossing locate (expert A), scalar-index shuffles ----
            int fpA = 0x7FFFFFFF;
            if ((avail >> eA) & 1u) {
                const int need = capA;
                int segc = -1, kk = 0;
                if (excl0A < need && excl0A + c0A >= need)      { segc = lane;      kk = need - excl0A; }
                else if (excl1A < need && excl1A + c1A >= need) { segc = 64 + lane; kk = need - excl1A; }
                unsigned long long bb = __ballot(segc >= 0);
                if (bb) {
                    const int l2    = __builtin_amdgcn_readfirstlane((int)__builtin_ctzll(bb));
                    const int sstar = __builtin_amdgcn_readlane(segc, l2);
                    const int k2    = __builtin_amdgcn_readlane(kk,   l2);
                    unsigned long long msel = (sstar < 64) ? rdlane64(a0, sstar)
                                                           : rdlane64(a1, sstar - 64);
                    int rr = (int)__popcll(msel & lt_mask);
                    bool hit = ((msel >> lane) & 1ull) && (rr == k2 - 1);
                    unsigned long long hb = __ballot(hit);
                    fpA = sstar * 64 + (int)__builtin_ctzll(hb);
                }
            }
            // ---- crossing locate (expert B) ----
            int fpB = 0x7FFFFFFF;
            if ((avail >> eB) & 1u) {
                const int need = capB;
                int segc = -1, kk = 0;
                if (excl0B < need && excl0B + c0B >= need)      { segc = lane;      kk = need - excl0B; }
                else if (excl1B < need && excl1B + c1B >= need) { segc = 64 + lane; kk = need - excl1B; }
                unsigned long long bb = __ballot(segc >= 0);
                if (bb) {
                    const int l2    = __builtin_amdgcn_readfirstlane((int)__builtin_ctzll(bb));
                    const int sstar = __builtin_amdgcn_readlane(segc, l2);
                    const int k2    = __builtin_amdgcn_readlane(kk,   l2);
                    unsigned long long msel = (sstar < 64) ? rdlane64(b0, sstar)
                                                           : rdlane64(b1, sstar - 64);
                    int rr = (int)__popcll(msel & lt_mask);
                    bool hit = ((msel >> lane) & 1ull) && (rr == k2 - 1);
                    unsigned long long hb = __ballot(hit);
                    fpB = sstar * 64 + (int)__builtin_ctzll(hb);
                }
            }
            if (lane == 0) { fparr[eA] = fpA; fparr[eB] = fpB; }
            __syncthreads();

            // ---- earliest fill event (redundant in all threads; same tie-break) ----
            int pmin = 0x7FFFFFFF, fe = 0;
            #pragma unroll
            for (int e = 0; e < N_EXP; ++e) {
                int f = fparr[e];
                if (f < pmin) { pmin = f; fe = e; }
            }
            if (tid == round) { myp = pmin; myf = fe; }

            const int nsegF = pmin >> 6;
            const unsigned long long nmlep = ((pmin & 63) == 63) ? ~0ull
                                             : ((1ull << ((pmin & 63) + 1)) - 1ull);
            const unsigned int navail = avail & ~(1u << fe);

            if (round < N_EXP - 1) {
                #pragma unroll
                for (int k = 0; k < 16; ++k) {
                    const int s = k * 8 + wave;
                    if (s >= nsegF) {
                        unsigned long long m = segmask[fe][s];
                        if (s == nsegF) m &= ~nmlep;
                        if ((m >> lane) & 1ull) {
                            unsigned long long pp = myPref[k];
                            int e2 = (int)(pp >> 60);
                            while (!((navail >> e2) & 1u)) { pp <<= 4; e2 = (int)(pp >> 60); }
                            atomicOr(&segmask[e2][s], 1ull << lane);
                        }
                    }
                }
            }
            segF = nsegF; mlep = nmlep; avail = navail;
            __syncthreads();
        }

        if (tid < N_EXP) {
            atomicExch(&evt[tid], myp);
            atomicExch(&evt[N_EXP + tid], myf);
        }
        // ================= end events body =================
    }

    // ---- grid barrier 1 (16 blocks; counter armed to 0 by K1) ----
    __syncthreads();
    if (tid == 0) {
        __threadfence();
        atomicAdd(&gsync[0], 1);
        while (atomicAdd(&gsync[0], 0) < 16) { __builtin_amdgcn_s_sleep(2); }
        __threadfence();
    }
    __syncthreads();

    // ---- choice phase: token t = b*512 + tid ----
    if (tid < N_EXP) evp[tid] = atomicAdd(&evt[tid], 0);
    else if (tid < 2 * N_EXP) evf[tid - N_EXP] = atomicAdd(&evt[tid], 0);
    __syncthreads();

    const int t = b * 512 + tid;
    unsigned int mask = 0xFFFFu;
    #pragma unroll
    for (int jj = 0; jj < N_EXP; ++jj)
        if (evp[jj] < t) mask &= ~(1u << evf[jj]);

    unsigned long long pp = pref[t];
    int e = (int)(pp >> 60);
    while (!((mask >> e) & 1u)) { pp <<= 4; e = (int)(pp >> 60); }

    unsigned long long own = 0ull;
    #pragma unroll
    for (int e2 = 0; e2 < N_EXP; ++e2) {
        unsigned long long mm = __ballot(e == e2);
        if (e == e2) own = mm;
        if (lane == e2) sc[wave][e2] = (int)__popcll(mm);
    }
    __syncthreads();

    if (tid < N_EXP) {
        int s = 0;
        #pragma unroll
        for (int w2 = 0; w2 < 8; ++w2) s += sc[w2][tid];
        atomicExch(&bcnt[b * N_EXP + tid], s);
    }

    // ---- grid barrier 2 ----
    __syncthreads();
    if (tid == 0) {
        __threadfence();
        atomicAdd(&gsync[1], 1);
        while (atomicAdd(&gsync[1], 0) < 16) { __builtin_amdgcn_s_sleep(2); }
        __threadfence();
    }
    __syncthreads();

    // ---- writeout phase: parallel gather of preceding blocks' counts ----
    for (int i = tid; i < b * N_EXP; i += 512)
        pcnt[i >> 4][i & 15] = atomicAdd(&bcnt[(i >> 4) * N_EXP + (i & 15)], 0);
    __syncthreads();
    if (tid < N_EXP) {
        int s = 0;
        for (int b2 = 0; b2 < b; ++b2) s += pcnt[b2][tid];
        base[tid] = s;
    }
    __syncthreads();

    int rank = (int)__popcll(own & lt_mask);
    for (int w2 = 0; w2 < wave; ++w2) rank += sc[w2][e];
    const int pos = base[e] + rank;
    out0[e * CAP + pos] = (float)t;
    out1[t] = probs[(size_t)t * N_EXP + e];
}

extern "C" void kernel_launch(void* const* d_in, const int* in_sizes, int n_in,
                              void* d_out, int out_size, void* d_ws, size_t ws_size,
                              hipStream_t stream) {
    const float* feat = (const float*)d_in[0];
    const float* W    = (const float*)d_in[1];
    const float* bias = (const float*)d_in[2];

    float* out = (float*)d_out;
    char*  ws  = (char*)d_ws;

    unsigned long long* pref = (unsigned long long*)(ws + 524288);
    float* probs             = (float*)(ws + 589824);
    int* evt                 = (int*)(ws + 1114112);
    int* gsync               = (int*)(ws + 1114240);
    int* bcnt                = (int*)(ws + 1122432);

    hipLaunchKernelGGL(gemm_finalize_kernel, dim3(T_TOK / 8), dim3(512), 0, stream,
                       feat, W, bias, pref, probs, gsync);
    hipLaunchKernelGGL(events_choice_write_kernel, dim3(16), dim3(512), 0, stream,
                       pref, probs, evt, gsync, bcnt, out, out + T_TOK);
}